// Round 1
// baseline (3828.040 us; speedup 1.0000x reference)
//
#include <hip/hip_runtime.h>
#include <cmath>

#define B_  4
#define DM  1024
#define LL  2048
#define HH  256

__device__ __forceinline__ float gelu_exact(float x) {
    return x * 0.5f * (1.0f + erff(x * 0.70710678118654752f));
}

// ---------------------------------------------------------------------------
// Kernel 1: build k_key (1024 x 2048) and k_v (256 x 2048)
// concat of 6 linearly-interpolated segments * 2^(5-i), then unit L2 norm.
// One block per channel. Segment layout: starts {0,64,128,256,512,1024},
// scales {1,1,2,4,8,16}.
// ---------------------------------------------------------------------------
__global__ __launch_bounds__(256) void build_kernels_kernel(
        const float* __restrict__ src_key,   // (6, 1024, 64)
        const float* __restrict__ src_v,     // (6, 256, 64)
        float* __restrict__ k_key,           // (1024, 2048)
        float* __restrict__ k_v) {           // (256, 2048)
    int bid = blockIdx.x;
    const float* src;
    float* dst;
    int chanstride;
    if (bid < DM) {
        src = src_key + (size_t)bid * 64;
        dst = k_key + (size_t)bid * LL;
        chanstride = DM * 64;
    } else {
        int c = bid - DM;
        src = src_v + (size_t)c * 64;
        dst = k_v + (size_t)c * LL;
        chanstride = HH * 64;
    }
    int t = threadIdx.x;
    float vals[8];
    float ss = 0.0f;
#pragma unroll
    for (int r = 0; r < 8; ++r) {
        int j = r * 256 + t;
        int i, start, scale;
        if (j < 64)        { i = 0; start = 0;    scale = 1;  }
        else if (j < 128)  { i = 1; start = 64;   scale = 1;  }
        else if (j < 256)  { i = 2; start = 128;  scale = 2;  }
        else if (j < 512)  { i = 3; start = 256;  scale = 4;  }
        else if (j < 1024) { i = 4; start = 512;  scale = 8;  }
        else               { i = 5; start = 1024; scale = 16; }
        int jj = j - start;
        float pos = ((float)jj + 0.5f) / (float)scale - 0.5f;
        pos = fminf(fmaxf(pos, 0.0f), 63.0f);
        int lo = (int)pos;            // pos >= 0 -> trunc == floor
        int hi = min(lo + 1, 63);
        float w = pos - (float)lo;
        const float* s = src + (size_t)i * chanstride;
        float x0 = s[lo], x1 = s[hi];
        float mult = (float)(1 << (5 - i));
        float vv = (x0 * (1.0f - w) + x1 * w) * mult;
        vals[r] = vv;
        ss += vv * vv;
    }
#pragma unroll
    for (int off = 32; off > 0; off >>= 1) ss += __shfl_down(ss, off, 64);
    __shared__ float red[4];
    __shared__ float norm_s;
    if ((t & 63) == 0) red[t >> 6] = ss;
    __syncthreads();
    if (t == 0) norm_s = sqrtf(red[0] + red[1] + red[2] + red[3]);
    __syncthreads();
    float nrm = norm_s;
#pragma unroll
    for (int r = 0; r < 8; ++r) {
        dst[r * 256 + t] = vals[r] / nrm;
    }
}

// ---------------------------------------------------------------------------
// Kernel 2: generic channel-GEMM  C[b,o,l] = bias[o] + sum_h W[o,h]*f(U[b,h,l])
// f = gelu if apply_gelu. 64x64 tile, 256 threads, 4x4 per thread.
// ---------------------------------------------------------------------------
__global__ __launch_bounds__(256) void gemm_nt(
        const float* __restrict__ W,     // (1024, 1024) row-major [o][h]
        const float* __restrict__ U,     // (B, 1024, 2048)
        const float* __restrict__ bias,  // (1024)
        float* __restrict__ C,           // (B, 1024, 2048)
        int apply_gelu) {
    __shared__ float Ws[16][68];
    __shared__ float Us[16][68];
    int l0 = blockIdx.x * 64;
    int o0 = blockIdx.y * 64;
    int b  = blockIdx.z;
    int t = threadIdx.x;
    int tx = t & 15, ty = t >> 4;
    float acc[4][4] = {};
    const float* Ub = U + (size_t)b * DM * LL;
    int oo = t >> 2, kb = (t & 3) * 4;
    int kku = t >> 4, lb = (t & 15) * 4;
    for (int h0 = 0; h0 < DM; h0 += 16) {
        float4 w4 = *(const float4*)(W + (size_t)(o0 + oo) * DM + h0 + kb);
        float4 u4 = *(const float4*)(Ub + (size_t)(h0 + kku) * LL + l0 + lb);
        if (apply_gelu) {
            u4.x = gelu_exact(u4.x); u4.y = gelu_exact(u4.y);
            u4.z = gelu_exact(u4.z); u4.w = gelu_exact(u4.w);
        }
        Ws[kb + 0][oo] = w4.x;
        Ws[kb + 1][oo] = w4.y;
        Ws[kb + 2][oo] = w4.z;
        Ws[kb + 3][oo] = w4.w;
        *(float4*)&Us[kku][lb] = u4;
        __syncthreads();
#pragma unroll
        for (int kk = 0; kk < 16; ++kk) {
            float4 a4 = *(const float4*)&Ws[kk][ty * 4];
            float4 b4 = *(const float4*)&Us[kk][tx * 4];
            float a[4] = {a4.x, a4.y, a4.z, a4.w};
            float bb[4] = {b4.x, b4.y, b4.z, b4.w};
#pragma unroll
            for (int i = 0; i < 4; ++i)
#pragma unroll
                for (int j = 0; j < 4; ++j)
                    acc[i][j] += a[i] * bb[j];
        }
        __syncthreads();
    }
#pragma unroll
    for (int i = 0; i < 4; ++i) {
        int o = o0 + ty * 4 + i;
        float bo = bias[o];
        float4 out;
        out.x = acc[i][0] + bo;
        out.y = acc[i][1] + bo;
        out.z = acc[i][2] + bo;
        out.w = acc[i][3] + bo;
        *(float4*)(C + ((size_t)b * DM + o) * LL + l0 + tx * 4) = out;
    }
}

// ---------------------------------------------------------------------------
// Kernel 3: key-side causal conv + skip.
// knew[b,c,l] = sum_{t<=l} kk[b,c,t]*k_key[c,l-t] + kk[b,c,l]*D_key[c]
// One block per (c, l-chunk of 256). 4 waves, lane owns one l, acc over 4 b's.
// ---------------------------------------------------------------------------
__global__ __launch_bounds__(256) void key_conv_kernel(
        const float* __restrict__ kk_raw,  // (B, 1024, 2048)
        const float* __restrict__ k_key,   // (1024, 2048)
        const float* __restrict__ D_key,   // (1024)
        float* __restrict__ knew) {        // (B, 1024, 2048)
    __shared__ float kkT[2048][4];  // 32 KB  [t][b]
    __shared__ float Kc[2048];      //  8 KB
    int bid = blockIdx.x;
    int c = bid >> 3, chunk = bid & 7;
    int lmax = (chunk + 1) * 256;
    int t = threadIdx.x;
#pragma unroll
    for (int d = 0; d < 4; ++d) {
        const float* p = kk_raw + ((size_t)d * DM + c) * LL;
        for (int j = t; j < lmax; j += 256) kkT[j][d] = p[j];
    }
    const float* kp = k_key + (size_t)c * LL;
    for (int j = t; j < lmax; j += 256) Kc[j] = kp[j];
    __syncthreads();
    int w = t >> 6, lane = t & 63;
    int l0 = chunk * 256 + w * 64;
    int l = l0 + lane;
    float a0 = 0, a1 = 0, a2 = 0, a3 = 0;
    int tend = l0 + 64;
    for (int tt = 0; tt < tend; ++tt) {
        float4 k4 = *(const float4*)&kkT[tt][0];  // wave-uniform broadcast
        int ki = l - tt;
        float kw = Kc[ki < 0 ? 0 : ki];
        kw = (ki < 0) ? 0.0f : kw;
        a0 += k4.x * kw; a1 += k4.y * kw; a2 += k4.z * kw; a3 += k4.w * kw;
    }
    float dk = D_key[c];
    float4 kl = *(const float4*)&kkT[l][0];
    knew[((size_t)0 * DM + c) * LL + l] = a0 + kl.x * dk;
    knew[((size_t)1 * DM + c) * LL + l] = a1 + kl.y * dk;
    knew[((size_t)2 * DM + c) * LL + l] = a2 + kl.z * dk;
    knew[((size_t)3 * DM + c) * LL + l] = a3 + kl.w * dk;
}

// ---------------------------------------------------------------------------
// Kernel 4: value-side gated conv, fused over d1,d2 (never materialize kv).
// y_g[b, d2*256+hh, l] = sum_d1 q[b,hh*4+d1,l] *
//        ( sum_{t<=l} k[b,hh*4+d1,t]*v[b,hh*4+d2,t]*k_v[hh,l-t]
//          + k[b,hh*4+d1,l]*v[b,hh*4+d2,l]*D[hh] )
// Block per (b, hh, l-chunk of 256); t staged in LDS tiles of 1024.
// ---------------------------------------------------------------------------
__global__ __launch_bounds__(256) void value_conv_kernel(
        const float* __restrict__ knew,  // (B, 1024, 2048)
        const float* __restrict__ v,     // (B, 1024, 2048)
        const float* __restrict__ q,     // (B, 1024, 2048)
        const float* __restrict__ k_v,   // (256, 2048)
        const float* __restrict__ Dv,    // (256)
        float* __restrict__ y_g) {       // (B, 1024, 2048), channel = d2*256+hh
    __shared__ float kT[1024][4];  // 16 KB  [t - t0][d1]
    __shared__ float vT[1024][4];  // 16 KB  [t - t0][d2]
    __shared__ float Kv[2048];     //  8 KB
    int bid = blockIdx.x;
    int chunk = bid & 7, hh = (bid >> 3) & 255, b = bid >> 11;
    int lmax = (chunk + 1) * 256;
    int t = threadIdx.x;
    const float* kvp = k_v + (size_t)hh * LL;
    for (int j = t; j < lmax; j += 256) Kv[j] = kvp[j];

    int w = t >> 6, lane = t & 63;
    int l0 = chunk * 256 + w * 64;
    int l = l0 + lane;
    int tend = l0 + 64;
    float acc[4][4] = {};

    const float* pk0 = knew + ((size_t)b * DM + hh * 4) * LL;
    const float* pv0 = v + ((size_t)b * DM + hh * 4) * LL;

    for (int t0 = 0; t0 < lmax; t0 += 1024) {
        int tbc = min(1024, lmax - t0);
        __syncthreads();  // previous tile's compute done (also covers Kv stage)
#pragma unroll
        for (int d = 0; d < 4; ++d) {
            const float* pk = pk0 + (size_t)d * LL;
            const float* pv = pv0 + (size_t)d * LL;
            for (int j = t; j < tbc; j += 256) {
                kT[j][d] = pk[t0 + j];
                vT[j][d] = pv[t0 + j];
            }
        }
        __syncthreads();
        int tstop = min(t0 + tbc, tend);
        for (int tt = t0; tt < tstop; ++tt) {
            float4 k4 = *(const float4*)&kT[tt - t0][0];  // broadcast
            float4 v4 = *(const float4*)&vT[tt - t0][0];  // broadcast
            int ki = l - tt;
            float kw = Kv[ki < 0 ? 0 : ki];
            kw = (ki < 0) ? 0.0f : kw;
            float p0 = k4.x * kw, p1 = k4.y * kw, p2 = k4.z * kw, p3 = k4.w * kw;
            acc[0][0] += p0 * v4.x; acc[0][1] += p0 * v4.y; acc[0][2] += p0 * v4.z; acc[0][3] += p0 * v4.w;
            acc[1][0] += p1 * v4.x; acc[1][1] += p1 * v4.y; acc[1][2] += p1 * v4.z; acc[1][3] += p1 * v4.w;
            acc[2][0] += p2 * v4.x; acc[2][1] += p2 * v4.y; acc[2][2] += p2 * v4.z; acc[2][3] += p2 * v4.w;
            acc[3][0] += p3 * v4.x; acc[3][1] += p3 * v4.y; acc[3][2] += p3 * v4.z; acc[3][3] += p3 * v4.w;
        }
    }
    // epilogue: D-skip + query gating (re-read k,v,q at position l from global)
    float Dh = Dv[hh];
    float klv[4], vlv[4], qv[4];
#pragma unroll
    for (int d = 0; d < 4; ++d) {
        klv[d] = pk0[(size_t)d * LL + l];
        vlv[d] = pv0[(size_t)d * LL + l];
        qv[d]  = q[((size_t)b * DM + hh * 4 + d) * LL + l];
    }
#pragma unroll
    for (int d2 = 0; d2 < 4; ++d2) {
        float y = qv[0] * (acc[0][d2] + klv[0] * vlv[d2] * Dh)
                + qv[1] * (acc[1][d2] + klv[1] * vlv[d2] * Dh)
                + qv[2] * (acc[2][d2] + klv[2] * vlv[d2] * Dh)
                + qv[3] * (acc[3][d2] + klv[3] * vlv[d2] * Dh);
        y_g[((size_t)b * DM + (size_t)d2 * 256 + hh) * LL + l] = y;
    }
}

// ---------------------------------------------------------------------------
extern "C" void kernel_launch(void* const* d_in, const int* in_sizes, int n_in,
                              void* d_out, int out_size, void* d_ws, size_t ws_size,
                              hipStream_t stream) {
    const float* u       = (const float*)d_in[0];
    const float* q_w     = (const float*)d_in[1];
    const float* q_b     = (const float*)d_in[2];
    const float* k_w     = (const float*)d_in[3];
    const float* k_b     = (const float*)d_in[4];
    const float* v_w     = (const float*)d_in[5];
    const float* v_b     = (const float*)d_in[6];
    const float* kern_k  = (const float*)d_in[7];   // (6,1024,64)
    const float* kern_v  = (const float*)d_in[8];   // (6,256,64)
    const float* D_key   = (const float*)d_in[9];   // (1,1024)
    const float* D_v     = (const float*)d_in[10];  // (1,256)
    const float* pw_w    = (const float*)d_in[11];
    const float* pw_b    = (const float*)d_in[12];
    float* out = (float*)d_out;

    float* ws = (float*)d_ws;
    const size_t SZ_KKEY = (size_t)DM * LL;        // 2,097,152
    const size_t SZ_KV   = (size_t)HH * LL;        //   524,288
    const size_t SZ_BDL  = (size_t)B_ * DM * LL;   // 8,388,608
    float* w_kkey = ws;
    float* w_kv   = w_kkey + SZ_KKEY;
    float* w_q    = w_kv + SZ_KV;
    float* w_kraw = w_q + SZ_BDL;
    float* w_v    = w_kraw + SZ_BDL;
    float* w_knew = w_v + SZ_BDL;
    float* w_yg   = w_kraw;  // reuse: kk_raw dead after key_conv

    // 1. build kernels
    build_kernels_kernel<<<DM + HH, 256, 0, stream>>>(kern_k, kern_v, w_kkey, w_kv);

    // 2. projections
    dim3 ggrid(LL / 64, DM / 64, B_);
    gemm_nt<<<ggrid, 256, 0, stream>>>(q_w, u, q_b, w_q, 0);
    gemm_nt<<<ggrid, 256, 0, stream>>>(k_w, u, k_b, w_kraw, 0);
    gemm_nt<<<ggrid, 256, 0, stream>>>(v_w, u, v_b, w_v, 0);

    // 3. key conv + skip
    key_conv_kernel<<<DM * 8, 256, 0, stream>>>(w_kraw, w_kkey, D_key, w_knew);

    // 4. value conv + gating (writes y_g over dead kk_raw)
    value_conv_kernel<<<B_ * HH * 8, 256, 0, stream>>>(w_knew, w_v, w_q, w_kv, D_v, w_yg);

    // 5. gelu + pointwise projection -> out
    gemm_nt<<<ggrid, 256, 0, stream>>>(pw_w, w_yg, pw_b, out, 1);
}

// Round 2
// 3401.243 us; speedup vs baseline: 1.1255x; 1.1255x over previous
//
#include <hip/hip_runtime.h>
#include <cmath>

#define B_  4
#define DM  1024
#define LL  2048
#define HH  256

__device__ __forceinline__ float gelu_exact(float x) {
    return x * 0.5f * (1.0f + erff(x * 0.70710678118654752f));
}

// ---------------------------------------------------------------------------
// Kernel 1: build k_key (1024 x 2048) and k_v (256 x 2048)
// ---------------------------------------------------------------------------
__global__ __launch_bounds__(256) void build_kernels_kernel(
        const float* __restrict__ src_key,   // (6, 1024, 64)
        const float* __restrict__ src_v,     // (6, 256, 64)
        float* __restrict__ k_key,           // (1024, 2048)
        float* __restrict__ k_v) {           // (256, 2048)
    int bid = blockIdx.x;
    const float* src;
    float* dst;
    int chanstride;
    if (bid < DM) {
        src = src_key + (size_t)bid * 64;
        dst = k_key + (size_t)bid * LL;
        chanstride = DM * 64;
    } else {
        int c = bid - DM;
        src = src_v + (size_t)c * 64;
        dst = k_v + (size_t)c * LL;
        chanstride = HH * 64;
    }
    int t = threadIdx.x;
    float vals[8];
    float ss = 0.0f;
#pragma unroll
    for (int r = 0; r < 8; ++r) {
        int j = r * 256 + t;
        int i, start, scale;
        if (j < 64)        { i = 0; start = 0;    scale = 1;  }
        else if (j < 128)  { i = 1; start = 64;   scale = 1;  }
        else if (j < 256)  { i = 2; start = 128;  scale = 2;  }
        else if (j < 512)  { i = 3; start = 256;  scale = 4;  }
        else if (j < 1024) { i = 4; start = 512;  scale = 8;  }
        else               { i = 5; start = 1024; scale = 16; }
        int jj = j - start;
        float pos = ((float)jj + 0.5f) / (float)scale - 0.5f;
        pos = fminf(fmaxf(pos, 0.0f), 63.0f);
        int lo = (int)pos;
        int hi = min(lo + 1, 63);
        float w = pos - (float)lo;
        const float* s = src + (size_t)i * chanstride;
        float x0 = s[lo], x1 = s[hi];
        float mult = (float)(1 << (5 - i));
        float vv = (x0 * (1.0f - w) + x1 * w) * mult;
        vals[r] = vv;
        ss += vv * vv;
    }
#pragma unroll
    for (int off = 32; off > 0; off >>= 1) ss += __shfl_down(ss, off, 64);
    __shared__ float red[4];
    __shared__ float norm_s;
    if ((t & 63) == 0) red[t >> 6] = ss;
    __syncthreads();
    if (t == 0) norm_s = sqrtf(red[0] + red[1] + red[2] + red[3]);
    __syncthreads();
    float nrm = norm_s;
#pragma unroll
    for (int r = 0; r < 8; ++r) {
        dst[r * 256 + t] = vals[r] / nrm;
    }
}

// ---------------------------------------------------------------------------
// Kernel 2: channel-GEMM  C[b,o,l] = bias[o] + sum_h W[o,h]*f(U[b,h,l])
// ---------------------------------------------------------------------------
__global__ __launch_bounds__(256) void gemm_nt(
        const float* __restrict__ W,     // (1024, 1024) row-major [o][h]
        const float* __restrict__ U,     // (B, 1024, 2048)
        const float* __restrict__ bias,  // (1024)
        float* __restrict__ C,           // (B, 1024, 2048)
        int apply_gelu) {
    __shared__ float Ws[16][68];
    __shared__ float Us[16][68];
    int l0 = blockIdx.x * 64;
    int o0 = blockIdx.y * 64;
    int b  = blockIdx.z;
    int t = threadIdx.x;
    int tx = t & 15, ty = t >> 4;
    float acc[4][4] = {};
    const float* Ub = U + (size_t)b * DM * LL;
    int oo = t >> 2, kb = (t & 3) * 4;
    int kku = t >> 4, lb = (t & 15) * 4;
    for (int h0 = 0; h0 < DM; h0 += 16) {
        float4 w4 = *(const float4*)(W + (size_t)(o0 + oo) * DM + h0 + kb);
        float4 u4 = *(const float4*)(Ub + (size_t)(h0 + kku) * LL + l0 + lb);
        if (apply_gelu) {
            u4.x = gelu_exact(u4.x); u4.y = gelu_exact(u4.y);
            u4.z = gelu_exact(u4.z); u4.w = gelu_exact(u4.w);
        }
        Ws[kb + 0][oo] = w4.x;
        Ws[kb + 1][oo] = w4.y;
        Ws[kb + 2][oo] = w4.z;
        Ws[kb + 3][oo] = w4.w;
        *(float4*)&Us[kku][lb] = u4;
        __syncthreads();
#pragma unroll
        for (int kk = 0; kk < 16; ++kk) {
            float4 a4 = *(const float4*)&Ws[kk][ty * 4];
            float4 b4 = *(const float4*)&Us[kk][tx * 4];
            float a[4] = {a4.x, a4.y, a4.z, a4.w};
            float bb[4] = {b4.x, b4.y, b4.z, b4.w};
#pragma unroll
            for (int i = 0; i < 4; ++i)
#pragma unroll
                for (int j = 0; j < 4; ++j)
                    acc[i][j] += a[i] * bb[j];
        }
        __syncthreads();
    }
#pragma unroll
    for (int i = 0; i < 4; ++i) {
        int o = o0 + ty * 4 + i;
        float bo = bias[o];
        float4 out;
        out.x = acc[i][0] + bo;
        out.y = acc[i][1] + bo;
        out.z = acc[i][2] + bo;
        out.w = acc[i][3] + bo;
        *(float4*)(C + ((size_t)b * DM + o) * LL + l0 + tx * 4) = out;
    }
}

// ---------------------------------------------------------------------------
// Kernel 3: key-side causal conv + skip.
// ---------------------------------------------------------------------------
__global__ __launch_bounds__(256) void key_conv_kernel(
        const float* __restrict__ kk_raw,  // (B, 1024, 2048)
        const float* __restrict__ k_key,   // (1024, 2048)
        const float* __restrict__ D_key,   // (1024)
        float* __restrict__ knew) {        // (B, 1024, 2048)
    __shared__ float kkT[2048][4];  // 32 KB  [t][b]
    __shared__ float Kc[2048];      //  8 KB
    int bid = blockIdx.x;
    int c = bid >> 3, chunk = bid & 7;
    int lmax = (chunk + 1) * 256;
    int t = threadIdx.x;
#pragma unroll
    for (int d = 0; d < 4; ++d) {
        const float* p = kk_raw + ((size_t)d * DM + c) * LL;
        for (int j = t; j < lmax; j += 256) kkT[j][d] = p[j];
    }
    const float* kp = k_key + (size_t)c * LL;
    for (int j = t; j < lmax; j += 256) Kc[j] = kp[j];
    __syncthreads();
    int w = t >> 6, lane = t & 63;
    int l0 = chunk * 256 + w * 64;
    int l = l0 + lane;
    float a0 = 0, a1 = 0, a2 = 0, a3 = 0;
    int tend = l0 + 64;
    for (int tt = 0; tt < tend; ++tt) {
        float4 k4 = *(const float4*)&kkT[tt][0];  // wave-uniform broadcast
        int ki = l - tt;
        float kw = Kc[ki < 0 ? 0 : ki];
        kw = (ki < 0) ? 0.0f : kw;
        a0 += k4.x * kw; a1 += k4.y * kw; a2 += k4.z * kw; a3 += k4.w * kw;
    }
    float dk = D_key[c];
    float4 kl = *(const float4*)&kkT[l][0];
    knew[((size_t)0 * DM + c) * LL + l] = a0 + kl.x * dk;
    knew[((size_t)1 * DM + c) * LL + l] = a1 + kl.y * dk;
    knew[((size_t)2 * DM + c) * LL + l] = a2 + kl.z * dk;
    knew[((size_t)3 * DM + c) * LL + l] = a3 + kl.w * dk;
}

// ---------------------------------------------------------------------------
// Kernel 4: value-side gated conv, fused over d1,d2.
// 4 l-positions per lane: block = (b, hh, half); lane owns
// l[i] = half*1024 + 256*i + tid.  acc[i][d1][d2] in 64 VGPRs.
// t-loop: full "history" tiles (no mask) + in-block tile in 4 regions
// (region j: i>=j active, i==j masked).
// ---------------------------------------------------------------------------
#define FMA16(I) \
    acc[I][0][0] += p0 * v4.x; acc[I][0][1] += p0 * v4.y; acc[I][0][2] += p0 * v4.z; acc[I][0][3] += p0 * v4.w; \
    acc[I][1][0] += p1 * v4.x; acc[I][1][1] += p1 * v4.y; acc[I][1][2] += p1 * v4.z; acc[I][1][3] += p1 * v4.w; \
    acc[I][2][0] += p2 * v4.x; acc[I][2][1] += p2 * v4.y; acc[I][2][2] += p2 * v4.z; acc[I][2][3] += p2 * v4.w; \
    acc[I][3][0] += p3 * v4.x; acc[I][3][1] += p3 * v4.y; acc[I][3][2] += p3 * v4.z; acc[I][3][3] += p3 * v4.w;

#define STEP_FULL(I) { \
    float kw = Kv[l[I] - tg]; \
    float p0 = k4.x * kw, p1 = k4.y * kw, p2 = k4.z * kw, p3 = k4.w * kw; \
    FMA16(I) }

#define STEP_MASK(I) { \
    int ki = l[I] - tg; \
    float kw = Kv[ki < 0 ? 0 : ki]; \
    kw = (ki < 0) ? 0.0f : kw; \
    float p0 = k4.x * kw, p1 = k4.y * kw, p2 = k4.z * kw, p3 = k4.w * kw; \
    FMA16(I) }

__global__ __launch_bounds__(256) void value_conv_kernel(
        const float* __restrict__ knew,  // (B, 1024, 2048)
        const float* __restrict__ v,     // (B, 1024, 2048)
        const float* __restrict__ q,     // (B, 1024, 2048)
        const float* __restrict__ k_v,   // (256, 2048)
        const float* __restrict__ Dv,    // (256)
        float* __restrict__ y_g) {       // (B, 1024, 2048), channel = d2*256+hh
    __shared__ float kT[1024][4];  // 16 KB  [t - t0][d1]
    __shared__ float vT[1024][4];  // 16 KB  [t - t0][d2]
    __shared__ float Kv[2048];     //  8 KB
    int bid = blockIdx.x;
    int half = bid & 1, hh = (bid >> 1) & 255, b = bid >> 9;
    int t = threadIdx.x;
    int l0b = half << 10;
    int l[4];
#pragma unroll
    for (int i = 0; i < 4; ++i) l[i] = l0b + (i << 8) + t;

    const float* kvp = k_v + (size_t)hh * LL;
#pragma unroll
    for (int j = 0; j < 8; ++j) Kv[t + j * 256] = kvp[t + j * 256];

    const float* pk0 = knew + ((size_t)b * DM + hh * 4) * LL;
    const float* pv0 = v + ((size_t)b * DM + hh * 4) * LL;
    float acc[4][4][4] = {};  // [i][d1][d2]

    int tmax = l0b + 1024;
    for (int t0 = 0; t0 < tmax; t0 += 1024) {
        __syncthreads();
#pragma unroll
        for (int d = 0; d < 4; ++d) {
            const float* pk = pk0 + (size_t)d * LL + t0;
            const float* pv = pv0 + (size_t)d * LL + t0;
#pragma unroll
            for (int j = 0; j < 4; ++j) {
                kT[t + j * 256][d] = pk[t + j * 256];
                vT[t + j * 256][d] = pv[t + j * 256];
            }
        }
        __syncthreads();
        if (t0 < l0b) {
            // full history tile: all 4 i active, no masking (l[i] >= l0b > tg)
            for (int tt = 0; tt < 1024; ++tt) {
                float4 k4 = *(const float4*)&kT[tt][0];
                float4 v4 = *(const float4*)&vT[tt][0];
                int tg = t0 + tt;
                STEP_FULL(0) STEP_FULL(1) STEP_FULL(2) STEP_FULL(3)
            }
        } else {
            // in-block tile (t0 == l0b): 4 regions of 256
            for (int tt = 0; tt < 256; ++tt) {
                float4 k4 = *(const float4*)&kT[tt][0];
                float4 v4 = *(const float4*)&vT[tt][0];
                int tg = t0 + tt;
                STEP_MASK(0) STEP_FULL(1) STEP_FULL(2) STEP_FULL(3)
            }
            for (int tt = 256; tt < 512; ++tt) {
                float4 k4 = *(const float4*)&kT[tt][0];
                float4 v4 = *(const float4*)&vT[tt][0];
                int tg = t0 + tt;
                STEP_MASK(1) STEP_FULL(2) STEP_FULL(3)
            }
            for (int tt = 512; tt < 768; ++tt) {
                float4 k4 = *(const float4*)&kT[tt][0];
                float4 v4 = *(const float4*)&vT[tt][0];
                int tg = t0 + tt;
                STEP_MASK(2) STEP_FULL(3)
            }
            for (int tt = 768; tt < 1024; ++tt) {
                float4 k4 = *(const float4*)&kT[tt][0];
                float4 v4 = *(const float4*)&vT[tt][0];
                int tg = t0 + tt;
                STEP_MASK(3)
            }
        }
    }

    // epilogue: D-skip + query gating; k(l), v(l) read from last LDS tile
    // (last staged tile covers [l0b, l0b+1024) which contains all l[i])
    float Dh = Dv[hh];
#pragma unroll
    for (int i = 0; i < 4; ++i) {
        int li = l[i];
        float4 kl4 = *(const float4*)&kT[li - l0b][0];
        float4 vl4 = *(const float4*)&vT[li - l0b][0];
        float qv[4];
#pragma unroll
        for (int d = 0; d < 4; ++d)
            qv[d] = q[((size_t)b * DM + hh * 4 + d) * LL + li];
        float kl[4] = {kl4.x, kl4.y, kl4.z, kl4.w};
        float vl[4] = {vl4.x, vl4.y, vl4.z, vl4.w};
#pragma unroll
        for (int d2 = 0; d2 < 4; ++d2) {
            float y = qv[0] * (acc[i][0][d2] + kl[0] * vl[d2] * Dh)
                    + qv[1] * (acc[i][1][d2] + kl[1] * vl[d2] * Dh)
                    + qv[2] * (acc[i][2][d2] + kl[2] * vl[d2] * Dh)
                    + qv[3] * (acc[i][3][d2] + kl[3] * vl[d2] * Dh);
            y_g[((size_t)b * DM + (size_t)d2 * 256 + hh) * LL + li] = y;
        }
    }
}

// ---------------------------------------------------------------------------
extern "C" void kernel_launch(void* const* d_in, const int* in_sizes, int n_in,
                              void* d_out, int out_size, void* d_ws, size_t ws_size,
                              hipStream_t stream) {
    const float* u       = (const float*)d_in[0];
    const float* q_w     = (const float*)d_in[1];
    const float* q_b     = (const float*)d_in[2];
    const float* k_w     = (const float*)d_in[3];
    const float* k_b     = (const float*)d_in[4];
    const float* v_w     = (const float*)d_in[5];
    const float* v_b     = (const float*)d_in[6];
    const float* kern_k  = (const float*)d_in[7];   // (6,1024,64)
    const float* kern_v  = (const float*)d_in[8];   // (6,256,64)
    const float* D_key   = (const float*)d_in[9];   // (1,1024)
    const float* D_v     = (const float*)d_in[10];  // (1,256)
    const float* pw_w    = (const float*)d_in[11];
    const float* pw_b    = (const float*)d_in[12];
    float* out = (float*)d_out;

    float* ws = (float*)d_ws;
    const size_t SZ_KKEY = (size_t)DM * LL;
    const size_t SZ_KV   = (size_t)HH * LL;
    const size_t SZ_BDL  = (size_t)B_ * DM * LL;
    float* w_kkey = ws;
    float* w_kv   = w_kkey + SZ_KKEY;
    float* w_q    = w_kv + SZ_KV;
    float* w_kraw = w_q + SZ_BDL;
    float* w_v    = w_kraw + SZ_BDL;
    float* w_knew = w_v + SZ_BDL;
    float* w_yg   = w_kraw;  // reuse: kk_raw dead after key_conv

    // 1. build kernels
    build_kernels_kernel<<<DM + HH, 256, 0, stream>>>(kern_k, kern_v, w_kkey, w_kv);

    // 2. projections
    dim3 ggrid(LL / 64, DM / 64, B_);
    gemm_nt<<<ggrid, 256, 0, stream>>>(q_w, u, q_b, w_q, 0);
    gemm_nt<<<ggrid, 256, 0, stream>>>(k_w, u, k_b, w_kraw, 0);
    gemm_nt<<<ggrid, 256, 0, stream>>>(v_w, u, v_b, w_v, 0);

    // 3. key conv + skip
    key_conv_kernel<<<DM * 8, 256, 0, stream>>>(w_kraw, w_kkey, D_key, w_knew);

    // 4. value conv + gating (writes y_g over dead kk_raw)
    value_conv_kernel<<<B_ * HH * 2, 256, 0, stream>>>(w_knew, w_v, w_q, w_kv, D_v, w_yg);

    // 5. gelu + pointwise projection -> out
    gemm_nt<<<ggrid, 256, 0, stream>>>(pw_w, w_yg, pw_b, out, 1);
}

// Round 3
// 1910.985 us; speedup vs baseline: 2.0032x; 1.7798x over previous
//
#include <hip/hip_runtime.h>
#include <cmath>

#define B_  4
#define DM  1024
#define LL  2048
#define HH  256

typedef short bf16x8 __attribute__((ext_vector_type(8)));
typedef float f32x4 __attribute__((ext_vector_type(4)));

__device__ __forceinline__ float gelu_exact(float x) {
    return x * 0.5f * (1.0f + erff(x * 0.70710678118654752f));
}
__device__ __forceinline__ unsigned short f2b(float f) {
    unsigned int x = __float_as_uint(f);
    unsigned int r = x + 0x7FFFu + ((x >> 16) & 1u);
    return (unsigned short)(r >> 16);
}
__device__ __forceinline__ float b2f(unsigned short u) {
    return __uint_as_float(((unsigned int)u) << 16);
}

// ---------------------------------------------------------------------------
// Kernel 1: build k_key (1024 x 2048, bf16) and k_v (256 x 2048, f32)
// ---------------------------------------------------------------------------
__global__ __launch_bounds__(256) void build_kernels_kernel(
        const float* __restrict__ src_key,   // (6, 1024, 64)
        const float* __restrict__ src_v,     // (6, 256, 64)
        unsigned short* __restrict__ k_key,  // (1024, 2048) bf16
        float* __restrict__ k_v) {           // (256, 2048) f32
    int bid = blockIdx.x;
    const float* src;
    int chanstride;
    bool is_key = bid < DM;
    if (is_key) {
        src = src_key + (size_t)bid * 64;
        chanstride = DM * 64;
    } else {
        src = src_v + (size_t)(bid - DM) * 64;
        chanstride = HH * 64;
    }
    int t = threadIdx.x;
    float vals[8];
    float ss = 0.0f;
#pragma unroll
    for (int r = 0; r < 8; ++r) {
        int j = r * 256 + t;
        int i, start, scale;
        if (j < 64)        { i = 0; start = 0;    scale = 1;  }
        else if (j < 128)  { i = 1; start = 64;   scale = 1;  }
        else if (j < 256)  { i = 2; start = 128;  scale = 2;  }
        else if (j < 512)  { i = 3; start = 256;  scale = 4;  }
        else if (j < 1024) { i = 4; start = 512;  scale = 8;  }
        else               { i = 5; start = 1024; scale = 16; }
        int jj = j - start;
        float pos = ((float)jj + 0.5f) / (float)scale - 0.5f;
        pos = fminf(fmaxf(pos, 0.0f), 63.0f);
        int lo = (int)pos;
        int hi = min(lo + 1, 63);
        float w = pos - (float)lo;
        const float* s = src + (size_t)i * chanstride;
        float x0 = s[lo], x1 = s[hi];
        float mult = (float)(1 << (5 - i));
        float vv = (x0 * (1.0f - w) + x1 * w) * mult;
        vals[r] = vv;
        ss += vv * vv;
    }
#pragma unroll
    for (int off = 32; off > 0; off >>= 1) ss += __shfl_down(ss, off, 64);
    __shared__ float red[4];
    __shared__ float norm_s;
    if ((t & 63) == 0) red[t >> 6] = ss;
    __syncthreads();
    if (t == 0) norm_s = sqrtf(red[0] + red[1] + red[2] + red[3]);
    __syncthreads();
    float nrm = norm_s;
    if (is_key) {
        unsigned short* dst = k_key + (size_t)bid * LL;
#pragma unroll
        for (int r = 0; r < 8; ++r) dst[r * 256 + t] = f2b(vals[r] / nrm);
    } else {
        float* dst = k_v + (size_t)(bid - DM) * LL;
#pragma unroll
        for (int r = 0; r < 8; ++r) dst[r * 256 + t] = vals[r] / nrm;
    }
}

// ---------------------------------------------------------------------------
// Kernel 2a: W f32 (1024x1024) -> bf16
// ---------------------------------------------------------------------------
__global__ __launch_bounds__(256) void wcvt_kernel(
        const float* __restrict__ src, unsigned short* __restrict__ dst) {
    int i = (blockIdx.x * 256 + threadIdx.x) * 4;
    float4 x = *(const float4*)(src + i);
    ushort4 o;
    o.x = f2b(x.x); o.y = f2b(x.y); o.z = f2b(x.z); o.w = f2b(x.w);
    *(ushort4*)(dst + i) = o;
}

// ---------------------------------------------------------------------------
// Kernel 2b: transpose+convert: src (B,1024,2048) f32 -> dst (B,2048,1024) bf16
// optional exact gelu applied before conversion.
// ---------------------------------------------------------------------------
__global__ __launch_bounds__(256) void transpose_cvt_kernel(
        const float* __restrict__ src, unsigned short* __restrict__ dst,
        int do_gelu) {
    __shared__ float tile[64][65];
    int l0 = blockIdx.x << 6;
    int h0 = blockIdx.y << 6;
    int b  = blockIdx.z;
    int t = threadIdx.x;
    int r = t >> 4, c4 = (t & 15) << 2;
    const float* s = src + ((size_t)b * DM + h0) * LL + l0;
#pragma unroll
    for (int p = 0; p < 4; ++p) {
        float4 x = *(const float4*)(s + (size_t)(p * 16 + r) * LL + c4);
        tile[p * 16 + r][c4 + 0] = x.x;
        tile[p * 16 + r][c4 + 1] = x.y;
        tile[p * 16 + r][c4 + 2] = x.z;
        tile[p * 16 + r][c4 + 3] = x.w;
    }
    __syncthreads();
    unsigned short* d = dst + ((size_t)b * LL + l0) * DM + h0;
#pragma unroll
    for (int p = 0; p < 4; ++p) {
        int lr = p * 16 + r;
        float x0 = tile[c4 + 0][lr];
        float x1 = tile[c4 + 1][lr];
        float x2 = tile[c4 + 2][lr];
        float x3 = tile[c4 + 3][lr];
        if (do_gelu) {
            x0 = gelu_exact(x0); x1 = gelu_exact(x1);
            x2 = gelu_exact(x2); x3 = gelu_exact(x3);
        }
        ushort4 o;
        o.x = f2b(x0); o.y = f2b(x1); o.z = f2b(x2); o.w = f2b(x3);
        *(ushort4*)(d + (size_t)lr * DM + c4) = o;
    }
}

// ---------------------------------------------------------------------------
// Kernel 3: MFMA GEMM.  C[b,o,l] = bias[o] + sum_h A[o,h] * Ubf[b,l,h]
// A (1024x1024) bf16 row-major (k-contig), Ubf (B,2048,1024) bf16 (k-contig).
// 128x128 tile, BK=64, 256 threads = 4 waves (2x2 of 64x64).
// ---------------------------------------------------------------------------
__global__ __launch_bounds__(256) void gemm_mfma_kernel(
        const unsigned short* __restrict__ A,
        const unsigned short* __restrict__ Ubf,
        const float* __restrict__ bias,
        float* __restrict__ C) {
    __shared__ unsigned short As[128 * 64];
    __shared__ unsigned short Bs[128 * 64];
    int bidx = blockIdx.x;
    int b = bidx >> 4;
    int n0 = (bidx & 15) << 7;
    int m0 = blockIdx.y << 7;
    int t = threadIdx.x;
    int lane = t & 63, wave = t >> 6;
    int wr = wave >> 1, wc = wave & 1;

    const unsigned short* Ub = Ubf + (size_t)b * LL * DM;

    f32x4 acc[4][4];
#pragma unroll
    for (int i = 0; i < 4; ++i)
#pragma unroll
        for (int j = 0; j < 4; ++j) {
            f32x4 z = {0.0f, 0.0f, 0.0f, 0.0f};
            acc[i][j] = z;
        }

    int srow = t >> 3;             // 0..31
    int scol = (t & 7) << 3;       // 0..56, 8 bf16 (16B) each

    int lrow = lane & 15;
    int lk = (lane >> 4) << 3;

    for (int k0 = 0; k0 < DM; k0 += 64) {
        __syncthreads();
#pragma unroll
        for (int p = 0; p < 4; ++p) {
            int row = p * 32 + srow;
            uint4 av = *(const uint4*)(A  + (size_t)(m0 + row) * DM + k0 + scol);
            uint4 bv = *(const uint4*)(Ub + (size_t)(n0 + row) * DM + k0 + scol);
            *(uint4*)&As[row * 64 + scol] = av;
            *(uint4*)&Bs[row * 64 + scol] = bv;
        }
        __syncthreads();
#pragma unroll
        for (int kk = 0; kk < 64; kk += 32) {
            bf16x8 af[4], bfr[4];
#pragma unroll
            for (int mi = 0; mi < 4; ++mi)
                af[mi] = *(const bf16x8*)&As[(wr * 64 + mi * 16 + lrow) * 64 + kk + lk];
#pragma unroll
            for (int ni = 0; ni < 4; ++ni)
                bfr[ni] = *(const bf16x8*)&Bs[(wc * 64 + ni * 16 + lrow) * 64 + kk + lk];
#pragma unroll
            for (int mi = 0; mi < 4; ++mi)
#pragma unroll
                for (int ni = 0; ni < 4; ++ni)
                    acc[mi][ni] = __builtin_amdgcn_mfma_f32_16x16x32_bf16(
                        af[mi], bfr[ni], acc[mi][ni], 0, 0, 0);
        }
    }
    int rg = (lane >> 4) << 2;
    int cn = lane & 15;
#pragma unroll
    for (int mi = 0; mi < 4; ++mi) {
#pragma unroll
        for (int r = 0; r < 4; ++r) {
            int o = m0 + wr * 64 + mi * 16 + rg + r;
            float bo = bias[o];
            float* crow = C + ((size_t)b * DM + o) * LL + n0 + wc * 64;
#pragma unroll
            for (int ni = 0; ni < 4; ++ni)
                crow[ni * 16 + cn] = acc[mi][ni][r] + bo;
        }
    }
}

// ---------------------------------------------------------------------------
// Kernel 4: key-side causal conv + skip (kkey bf16 in, all else f32).
// Wave w of block (c, chunk) handles l-segment (chunk + 8w)*64 — balanced.
// ---------------------------------------------------------------------------
__global__ __launch_bounds__(256) void key_conv_kernel(
        const float* __restrict__ kk_raw,        // (B, 1024, 2048)
        const unsigned short* __restrict__ k_key,// (1024, 2048) bf16
        const float* __restrict__ D_key,         // (1024)
        float* __restrict__ knew) {              // (B, 1024, 2048)
    __shared__ float kkT[2048][4];  // 32 KB
    __shared__ float Kc[2048];      //  8 KB
    int bid = blockIdx.x;
    int c = bid >> 3, chunk = bid & 7;
    int lmax_b = (chunk + 24) * 64 + 64;   // covers the largest wave segment
    int t = threadIdx.x;
#pragma unroll
    for (int d = 0; d < 4; ++d) {
        const float* p = kk_raw + ((size_t)d * DM + c) * LL;
        for (int j = t; j < lmax_b; j += 256) kkT[j][d] = p[j];
    }
    const unsigned short* kp = k_key + (size_t)c * LL;
    for (int j = t; j < lmax_b; j += 256) Kc[j] = b2f(kp[j]);
    __syncthreads();
    int w = t >> 6, lane = t & 63;
    int l0 = (chunk + 8 * w) * 64;
    int l = l0 + lane;
    float a0 = 0, a1 = 0, a2 = 0, a3 = 0;
    int tend = l0 + 64;
    for (int tt = 0; tt < tend; ++tt) {
        float4 k4 = *(const float4*)&kkT[tt][0];  // wave-uniform broadcast
        int ki = l - tt;
        float kw = Kc[ki < 0 ? 0 : ki];
        kw = (ki < 0) ? 0.0f : kw;
        a0 += k4.x * kw; a1 += k4.y * kw; a2 += k4.z * kw; a3 += k4.w * kw;
    }
    float dk = D_key[c];
    float4 kl = *(const float4*)&kkT[l][0];
    knew[((size_t)0 * DM + c) * LL + l] = a0 + kl.x * dk;
    knew[((size_t)1 * DM + c) * LL + l] = a1 + kl.y * dk;
    knew[((size_t)2 * DM + c) * LL + l] = a2 + kl.z * dk;
    knew[((size_t)3 * DM + c) * LL + l] = a3 + kl.w * dk;
}

// ---------------------------------------------------------------------------
// Kernel 5: value-side gated conv, fused over d1,d2 — balanced stratified l.
// Block (b, hh, off): lane owns l[i] = i*512 + off*256 + t, i=0..3.
// Tiles of 512 t's; per tile j: i<j skip, i>j full, i==j partial.
// ---------------------------------------------------------------------------
#define FMA16(I) \
    acc[I][0][0] += p0 * v4.x; acc[I][0][1] += p0 * v4.y; acc[I][0][2] += p0 * v4.z; acc[I][0][3] += p0 * v4.w; \
    acc[I][1][0] += p1 * v4.x; acc[I][1][1] += p1 * v4.y; acc[I][1][2] += p1 * v4.z; acc[I][1][3] += p1 * v4.w; \
    acc[I][2][0] += p2 * v4.x; acc[I][2][1] += p2 * v4.y; acc[I][2][2] += p2 * v4.z; acc[I][2][3] += p2 * v4.w; \
    acc[I][3][0] += p3 * v4.x; acc[I][3][1] += p3 * v4.y; acc[I][3][2] += p3 * v4.z; acc[I][3][3] += p3 * v4.w;

#define STEP_FULL(I) { \
    float kw = Kv[l[I] - tg]; \
    float p0 = k4.x * kw, p1 = k4.y * kw, p2 = k4.z * kw, p3 = k4.w * kw; \
    FMA16(I) }

#define STEP_MASK(I) { \
    int ki = l[I] - tg; \
    float kw = Kv[ki < 0 ? 0 : ki]; \
    kw = (ki < 0) ? 0.0f : kw; \
    float p0 = k4.x * kw, p1 = k4.y * kw, p2 = k4.z * kw, p3 = k4.w * kw; \
    FMA16(I) }

#define DO_TILE(J, ...) do { \
    __syncthreads(); \
    _Pragma("unroll") \
    for (int d = 0; d < 4; ++d) { \
        const float* pkd = pk0 + (size_t)d * LL + (J) * 512; \
        const float* pvd = pv0 + (size_t)d * LL + (J) * 512; \
        kT[t][d]       = pkd[t]; \
        kT[t + 256][d] = pkd[t + 256]; \
        vT[t][d]       = pvd[t]; \
        vT[t + 256][d] = pvd[t + 256]; \
    } \
    __syncthreads(); \
    if (off == 0) { \
        for (int tt = 0; tt < 256; ++tt) { \
            float4 k4 = *(const float4*)&kT[tt][0]; \
            float4 v4 = *(const float4*)&vT[tt][0]; \
            int tg = (J) * 512 + tt; \
            STEP_MASK(J) \
            __VA_ARGS__ \
        } \
        for (int tt = 256; tt < 512; ++tt) { \
            float4 k4 = *(const float4*)&kT[tt][0]; \
            float4 v4 = *(const float4*)&vT[tt][0]; \
            int tg = (J) * 512 + tt; \
            __VA_ARGS__ \
        } \
    } else { \
        for (int tt = 0; tt < 256; ++tt) { \
            float4 k4 = *(const float4*)&kT[tt][0]; \
            float4 v4 = *(const float4*)&vT[tt][0]; \
            int tg = (J) * 512 + tt; \
            STEP_FULL(J) \
            __VA_ARGS__ \
        } \
        for (int tt = 256; tt < 512; ++tt) { \
            float4 k4 = *(const float4*)&kT[tt][0]; \
            float4 v4 = *(const float4*)&vT[tt][0]; \
            int tg = (J) * 512 + tt; \
            STEP_MASK(J) \
            __VA_ARGS__ \
        } \
    } \
} while (0)

__global__ __launch_bounds__(256) void value_conv_kernel(
        const float* __restrict__ knew,  // (B, 1024, 2048)
        const float* __restrict__ v,     // (B, 1024, 2048)
        const float* __restrict__ q,     // (B, 1024, 2048)
        const float* __restrict__ k_v,   // (256, 2048)
        const float* __restrict__ Dv,    // (256)
        float* __restrict__ y_g) {       // (B, 1024, 2048), channel = d2*256+hh
    __shared__ float kT[512][4];   // 8 KB
    __shared__ float vT[512][4];   // 8 KB
    __shared__ float Kv[2048];     // 8 KB
    int bid = blockIdx.x;
    int off = bid & 1, hh = (bid >> 1) & 255, b = bid >> 9;
    int t = threadIdx.x;
    int l[4];
#pragma unroll
    for (int i = 0; i < 4; ++i) l[i] = (i << 9) + (off << 8) + t;

    const float* kvp = k_v + (size_t)hh * LL;
#pragma unroll
    for (int j = 0; j < 8; ++j) Kv[t + j * 256] = kvp[t + j * 256];

    const float* pk0 = knew + ((size_t)b * DM + hh * 4) * LL;
    const float* pv0 = v + ((size_t)b * DM + hh * 4) * LL;
    float acc[4][4][4] = {};  // [i][d1][d2]

    DO_TILE(0, STEP_FULL(1) STEP_FULL(2) STEP_FULL(3));
    DO_TILE(1, STEP_FULL(2) STEP_FULL(3));
    DO_TILE(2, STEP_FULL(3));
    DO_TILE(3, );

    // epilogue: D-skip + query gating (global reads at position l[i])
    float Dh = Dv[hh];
#pragma unroll
    for (int i = 0; i < 4; ++i) {
        int li = l[i];
        float kl[4], vl[4], qv[4];
#pragma unroll
        for (int d = 0; d < 4; ++d) {
            kl[d] = pk0[(size_t)d * LL + li];
            vl[d] = pv0[(size_t)d * LL + li];
            qv[d] = q[((size_t)b * DM + hh * 4 + d) * LL + li];
        }
#pragma unroll
        for (int d2 = 0; d2 < 4; ++d2) {
            float y = qv[0] * (acc[i][0][d2] + kl[0] * vl[d2] * Dh)
                    + qv[1] * (acc[i][1][d2] + kl[1] * vl[d2] * Dh)
                    + qv[2] * (acc[i][2][d2] + kl[2] * vl[d2] * Dh)
                    + qv[3] * (acc[i][3][d2] + kl[3] * vl[d2] * Dh);
            y_g[((size_t)b * DM + (size_t)d2 * 256 + hh) * LL + li] = y;
        }
    }
}

// ---------------------------------------------------------------------------
extern "C" void kernel_launch(void* const* d_in, const int* in_sizes, int n_in,
                              void* d_out, int out_size, void* d_ws, size_t ws_size,
                              hipStream_t stream) {
    const float* u       = (const float*)d_in[0];
    const float* q_w     = (const float*)d_in[1];
    const float* q_b     = (const float*)d_in[2];
    const float* k_w     = (const float*)d_in[3];
    const float* k_b     = (const float*)d_in[4];
    const float* v_w     = (const float*)d_in[5];
    const float* v_b     = (const float*)d_in[6];
    const float* kern_k  = (const float*)d_in[7];
    const float* kern_v  = (const float*)d_in[8];
    const float* D_key   = (const float*)d_in[9];
    const float* D_v     = (const float*)d_in[10];
    const float* pw_w    = (const float*)d_in[11];
    const float* pw_b    = (const float*)d_in[12];
    float* out = (float*)d_out;

    const size_t BDL = (size_t)B_ * DM * LL;
    char* p = (char*)d_ws;
    float*          w_kv   = (float*)p;          p += (size_t)HH * LL * 4;   // 2 MiB
    unsigned short* w_kkey = (unsigned short*)p; p += (size_t)DM * LL * 2;   // 4 MiB
    unsigned short* w_wbuf = (unsigned short*)p; p += (size_t)DM * DM * 2;   // 2 MiB
    float*          w_R0   = (float*)p;          p += BDL * 4;               // 32 MiB (knew / u_T / yg_T)
    float*          w_q    = (float*)p;          p += BDL * 4;               // 32 MiB
    float*          w_ky   = (float*)p;          p += BDL * 4;               // 32 MiB (kraw -> y_g)
    float*          w_v    = (float*)p;          p += BDL * 4;               // 32 MiB
    unsigned short* w_uT   = (unsigned short*)w_R0;   // lives before knew
    unsigned short* w_ygT  = (unsigned short*)w_R0;   // lives after knew
    float*          w_knew = w_R0;
    float*          w_yg   = w_ky;

    // 1. build kernels
    build_kernels_kernel<<<DM + HH, 256, 0, stream>>>(kern_k, kern_v, w_kkey, w_kv);

    // 2. u -> u_T bf16
    dim3 tgrid(LL / 64, DM / 64, B_);
    transpose_cvt_kernel<<<tgrid, 256, 0, stream>>>(u, w_uT, 0);

    // 3. projections (bf16 MFMA)
    dim3 ggrid(B_ * (LL / 128), DM / 128);
    wcvt_kernel<<<DM * DM / 1024, 256, 0, stream>>>(q_w, w_wbuf);
    gemm_mfma_kernel<<<ggrid, 256, 0, stream>>>(w_wbuf, w_uT, q_b, w_q);
    wcvt_kernel<<<DM * DM / 1024, 256, 0, stream>>>(k_w, w_wbuf);
    gemm_mfma_kernel<<<ggrid, 256, 0, stream>>>(w_wbuf, w_uT, k_b, w_ky);
    wcvt_kernel<<<DM * DM / 1024, 256, 0, stream>>>(v_w, w_wbuf);
    gemm_mfma_kernel<<<ggrid, 256, 0, stream>>>(w_wbuf, w_uT, v_b, w_v);

    // 4. key conv + skip (u_T dead; knew takes over R0)
    key_conv_kernel<<<DM * 8, 256, 0, stream>>>(w_ky, w_kkey, D_key, w_knew);

    // 5. value conv + gating (y_g overwrites kraw)
    value_conv_kernel<<<B_ * HH * 2, 256, 0, stream>>>(w_knew, w_v, w_q, w_kv, D_v, w_yg);

    // 6. y_g -> gelu -> yg_T bf16 (knew dead; yg_T takes over R0)
    transpose_cvt_kernel<<<tgrid, 256, 0, stream>>>(w_yg, w_ygT, 1);

    // 7. pointwise projection
    wcvt_kernel<<<DM * DM / 1024, 256, 0, stream>>>(pw_w, w_wbuf);
    gemm_mfma_kernel<<<ggrid, 256, 0, stream>>>(w_wbuf, w_ygT, pw_b, out);
}

// Round 5
// 1048.328 us; speedup vs baseline: 3.6516x; 1.8229x over previous
//
#include <hip/hip_runtime.h>
#include <cmath>

#define B_  4
#define DM  1024
#define LL  2048
#define HH  256

typedef short bf16x8 __attribute__((ext_vector_type(8)));
typedef float f32x4 __attribute__((ext_vector_type(4)));

__device__ __forceinline__ float gelu_exact(float x) {
    return x * 0.5f * (1.0f + erff(x * 0.70710678118654752f));
}
__device__ __forceinline__ unsigned short f2b(float f) {
    unsigned int x = __float_as_uint(f);
    unsigned int r = x + 0x7FFFu + ((x >> 16) & 1u);
    return (unsigned short)(r >> 16);
}
__device__ __forceinline__ float b2f(unsigned short u) {
    return __uint_as_float(((unsigned int)u) << 16);
}
__device__ __forceinline__ int cvt_pk_bf16(float lo, float hi) {
    int r;
    asm("v_cvt_pk_bf16_f32 %0, %1, %2" : "=v"(r) : "v"(lo), "v"(hi));
    return r;
}

// ---------------------------------------------------------------------------
// Kernel 1: build k_key (1024 x 2048, bf16) and k_v (256 x 2048, f32)
// ---------------------------------------------------------------------------
__global__ __launch_bounds__(256) void build_kernels_kernel(
        const float* __restrict__ src_key,   // (6, 1024, 64)
        const float* __restrict__ src_v,     // (6, 256, 64)
        unsigned short* __restrict__ k_key,  // (1024, 2048) bf16
        float* __restrict__ k_v) {           // (256, 2048) f32
    int bid = blockIdx.x;
    const float* src;
    int chanstride;
    bool is_key = bid < DM;
    if (is_key) {
        src = src_key + (size_t)bid * 64;
        chanstride = DM * 64;
    } else {
        src = src_v + (size_t)(bid - DM) * 64;
        chanstride = HH * 64;
    }
    int t = threadIdx.x;
    float vals[8];
    float ss = 0.0f;
#pragma unroll
    for (int r = 0; r < 8; ++r) {
        int j = r * 256 + t;
        int i, start, scale;
        if (j < 64)        { i = 0; start = 0;    scale = 1;  }
        else if (j < 128)  { i = 1; start = 64;   scale = 1;  }
        else if (j < 256)  { i = 2; start = 128;  scale = 2;  }
        else if (j < 512)  { i = 3; start = 256;  scale = 4;  }
        else if (j < 1024) { i = 4; start = 512;  scale = 8;  }
        else               { i = 5; start = 1024; scale = 16; }
        int jj = j - start;
        float pos = ((float)jj + 0.5f) / (float)scale - 0.5f;
        pos = fminf(fmaxf(pos, 0.0f), 63.0f);
        int lo = (int)pos;
        int hi = min(lo + 1, 63);
        float w = pos - (float)lo;
        const float* s = src + (size_t)i * chanstride;
        float x0 = s[lo], x1 = s[hi];
        float mult = (float)(1 << (5 - i));
        float vv = (x0 * (1.0f - w) + x1 * w) * mult;
        vals[r] = vv;
        ss += vv * vv;
    }
#pragma unroll
    for (int off = 32; off > 0; off >>= 1) ss += __shfl_down(ss, off, 64);
    __shared__ float red[4];
    __shared__ float norm_s;
    if ((t & 63) == 0) red[t >> 6] = ss;
    __syncthreads();
    if (t == 0) norm_s = sqrtf(red[0] + red[1] + red[2] + red[3]);
    __syncthreads();
    float nrm = norm_s;
    if (is_key) {
        unsigned short* dst = k_key + (size_t)bid * LL;
#pragma unroll
        for (int r = 0; r < 8; ++r) dst[r * 256 + t] = f2b(vals[r] / nrm);
    } else {
        float* dst = k_v + (size_t)(bid - DM) * LL;
#pragma unroll
        for (int r = 0; r < 8; ++r) dst[r * 256 + t] = vals[r] / nrm;
    }
}

// ---------------------------------------------------------------------------
// Kernel 2a: W f32 (1024x1024) -> bf16
// ---------------------------------------------------------------------------
__global__ __launch_bounds__(256) void wcvt_kernel(
        const float* __restrict__ src, unsigned short* __restrict__ dst) {
    int i = (blockIdx.x * 256 + threadIdx.x) * 4;
    float4 x = *(const float4*)(src + i);
    ushort4 o;
    o.x = f2b(x.x); o.y = f2b(x.y); o.z = f2b(x.z); o.w = f2b(x.w);
    *(ushort4*)(dst + i) = o;
}

// ---------------------------------------------------------------------------
// Kernel 2b: transpose+convert: src (B,1024,2048) f32 -> dst (B,2048,1024) bf16
// ---------------------------------------------------------------------------
__global__ __launch_bounds__(256) void transpose_cvt_kernel(
        const float* __restrict__ src, unsigned short* __restrict__ dst,
        int do_gelu) {
    __shared__ float tile[64][65];
    int l0 = blockIdx.x << 6;
    int h0 = blockIdx.y << 6;
    int b  = blockIdx.z;
    int t = threadIdx.x;
    int r = t >> 4, c4 = (t & 15) << 2;
    const float* s = src + ((size_t)b * DM + h0) * LL + l0;
#pragma unroll
    for (int p = 0; p < 4; ++p) {
        float4 x = *(const float4*)(s + (size_t)(p * 16 + r) * LL + c4);
        tile[p * 16 + r][c4 + 0] = x.x;
        tile[p * 16 + r][c4 + 1] = x.y;
        tile[p * 16 + r][c4 + 2] = x.z;
        tile[p * 16 + r][c4 + 3] = x.w;
    }
    __syncthreads();
    unsigned short* d = dst + ((size_t)b * LL + l0) * DM + h0;
#pragma unroll
    for (int p = 0; p < 4; ++p) {
        int lr = p * 16 + r;
        float x0 = tile[c4 + 0][lr];
        float x1 = tile[c4 + 1][lr];
        float x2 = tile[c4 + 2][lr];
        float x3 = tile[c4 + 3][lr];
        if (do_gelu) {
            x0 = gelu_exact(x0); x1 = gelu_exact(x1);
            x2 = gelu_exact(x2); x3 = gelu_exact(x3);
        }
        ushort4 o;
        o.x = f2b(x0); o.y = f2b(x1); o.z = f2b(x2); o.w = f2b(x3);
        *(ushort4*)(d + (size_t)lr * DM + c4) = o;
    }
}

// ---------------------------------------------------------------------------
// Kernel 3: MFMA GEMM.  C[b,o,l] = bias[o] + sum_h A[o,h] * Ubf[b,l,h]
// ---------------------------------------------------------------------------
__global__ __launch_bounds__(256) void gemm_mfma_kernel(
        const unsigned short* __restrict__ A,
        const unsigned short* __restrict__ Ubf,
        const float* __restrict__ bias,
        float* __restrict__ C) {
    __shared__ unsigned short As[128 * 64];
    __shared__ unsigned short Bs[128 * 64];
    int bidx = blockIdx.x;
    int b = bidx >> 4;
    int n0 = (bidx & 15) << 7;
    int m0 = blockIdx.y << 7;
    int t = threadIdx.x;
    int lane = t & 63, wave = t >> 6;
    int wr = wave >> 1, wc = wave & 1;

    const unsigned short* Ub = Ubf + (size_t)b * LL * DM;

    f32x4 acc[4][4];
#pragma unroll
    for (int i = 0; i < 4; ++i)
#pragma unroll
        for (int j = 0; j < 4; ++j) {
            f32x4 z = {0.0f, 0.0f, 0.0f, 0.0f};
            acc[i][j] = z;
        }

    int srow = t >> 3;
    int scol = (t & 7) << 3;
    int lrow = lane & 15;
    int lk = (lane >> 4) << 3;

    for (int k0 = 0; k0 < DM; k0 += 64) {
        __syncthreads();
#pragma unroll
        for (int p = 0; p < 4; ++p) {
            int row = p * 32 + srow;
            uint4 av = *(const uint4*)(A  + (size_t)(m0 + row) * DM + k0 + scol);
            uint4 bv = *(const uint4*)(Ub + (size_t)(n0 + row) * DM + k0 + scol);
            *(uint4*)&As[row * 64 + scol] = av;
            *(uint4*)&Bs[row * 64 + scol] = bv;
        }
        __syncthreads();
#pragma unroll
        for (int kk = 0; kk < 64; kk += 32) {
            bf16x8 af[4], bfr[4];
#pragma unroll
            for (int mi = 0; mi < 4; ++mi)
                af[mi] = *(const bf16x8*)&As[(wr * 64 + mi * 16 + lrow) * 64 + kk + lk];
#pragma unroll
            for (int ni = 0; ni < 4; ++ni)
                bfr[ni] = *(const bf16x8*)&Bs[(wc * 64 + ni * 16 + lrow) * 64 + kk + lk];
#pragma unroll
            for (int mi = 0; mi < 4; ++mi)
#pragma unroll
                for (int ni = 0; ni < 4; ++ni)
                    acc[mi][ni] = __builtin_amdgcn_mfma_f32_16x16x32_bf16(
                        af[mi], bfr[ni], acc[mi][ni], 0, 0, 0);
        }
    }
    int rg = (lane >> 4) << 2;
    int cn = lane & 15;
#pragma unroll
    for (int mi = 0; mi < 4; ++mi) {
#pragma unroll
        for (int r = 0; r < 4; ++r) {
            int o = m0 + wr * 64 + mi * 16 + rg + r;
            float bo = bias[o];
            float* crow = C + ((size_t)b * DM + o) * LL + n0 + wc * 64;
#pragma unroll
            for (int ni = 0; ni < 4; ++ni)
                crow[ni * 16 + cn] = acc[mi][ni][r] + bo;
        }
    }
}

// ---------------------------------------------------------------------------
// Kernel 4: key-side causal conv + skip (f32 VALU, balanced waves).
// ---------------------------------------------------------------------------
__global__ __launch_bounds__(256) void key_conv_kernel(
        const float* __restrict__ kk_raw,
        const unsigned short* __restrict__ k_key,
        const float* __restrict__ D_key,
        float* __restrict__ knew) {
    __shared__ float kkT[2048][4];
    __shared__ float Kc[2048];
    int bid = blockIdx.x;
    int c = bid >> 3, chunk = bid & 7;
    int lmax_b = (chunk + 24) * 64 + 64;
    int t = threadIdx.x;
#pragma unroll
    for (int d = 0; d < 4; ++d) {
        const float* p = kk_raw + ((size_t)d * DM + c) * LL;
        for (int j = t; j < lmax_b; j += 256) kkT[j][d] = p[j];
    }
    const unsigned short* kp = k_key + (size_t)c * LL;
    for (int j = t; j < lmax_b; j += 256) Kc[j] = b2f(kp[j]);
    __syncthreads();
    int w = t >> 6, lane = t & 63;
    int l0 = (chunk + 8 * w) * 64;
    int l = l0 + lane;
    float a0 = 0, a1 = 0, a2 = 0, a3 = 0;
    int tend = l0 + 64;
    for (int tt = 0; tt < tend; ++tt) {
        float4 k4 = *(const float4*)&kkT[tt][0];
        int ki = l - tt;
        float kw = Kc[ki < 0 ? 0 : ki];
        kw = (ki < 0) ? 0.0f : kw;
        a0 += k4.x * kw; a1 += k4.y * kw; a2 += k4.z * kw; a3 += k4.w * kw;
    }
    float dk = D_key[c];
    float4 kl = *(const float4*)&kkT[l][0];
    knew[((size_t)0 * DM + c) * LL + l] = a0 + kl.x * dk;
    knew[((size_t)1 * DM + c) * LL + l] = a1 + kl.y * dk;
    knew[((size_t)2 * DM + c) * LL + l] = a2 + kl.z * dk;
    knew[((size_t)3 * DM + c) * LL + l] = a3 + kl.w * dk;
}

// ---------------------------------------------------------------------------
// Kernel 5: value-side gated conv via Toeplitz MFMA.
// Per block (b, hh): y[dd=16][l=2048] = sum_{t'} kv'[dd,t'] * Kpad[l + t' - 1999]
// where kv'[dd,t'] = knew[d1, 2047-t'] * v[d2, 2047-t'] (t-axis reversed so
// B-fragment reads ascend), Kpad[j] = (j>=48) ? K_v[hh][j-48] : 0.
// 8 waves; wave w owns l-tiles l0 = 16w + 128m, m = 0..15.
// MFMA 16x16x32: A = kv' (M=dd), B = Toeplitz tile (N=l). acc: 16 x f32x4.
// Epilogue: D-skip + q-gating, sum over d1 via shfl_xor(16,32).
// ---------------------------------------------------------------------------
__global__ __launch_bounds__(512) void value_conv_mfma_kernel(
        const float* __restrict__ knew,  // (B, 1024, 2048)
        const float* __restrict__ v,     // (B, 1024, 2048)
        const float* __restrict__ q,     // (B, 1024, 2048)
        const float* __restrict__ k_v,   // (256, 2048) f32
        const float* __restrict__ Dv,    // (256)
        float* __restrict__ y_g) {       // (B, 1024, 2048), channel = d2*256+hh
    __shared__ float Kpad[2096];
    int bid = blockIdx.x;
    int hh = bid & 255, b = bid >> 8;
    int tid = threadIdx.x;

    const float* kvp = k_v + (size_t)hh * LL;
    for (int j = tid; j < 2096; j += 512)
        Kpad[j] = (j >= 48) ? kvp[j - 48] : 0.0f;
    __syncthreads();

    int w = tid >> 6, lane = tid & 63;
    int n = lane & 15, kgrp = lane >> 4;
    int d1a = n >> 2, d2a = n & 3;   // A-operand row decomposition

    const float* pk = knew + ((size_t)b * DM + hh * 4 + d1a) * LL;
    const float* pv = v    + ((size_t)b * DM + hh * 4 + d2a) * LL;

    f32x4 acc[16];
#pragma unroll
    for (int m = 0; m < 16; ++m) {
        f32x4 z = {0.0f, 0.0f, 0.0f, 0.0f};
        acc[m] = z;
    }

    // Kpad index at (s=0, m=0): (16w + 128m + n) + (32s + 8kgrp + e) - 2047 + 48
    int idx0 = 16 * w + n + 8 * kgrp - 1999;

    for (int s = 0; s < 64; ++s) {
        int t0p = s << 5;
        // ---- A fragment: elem e -> t' = t0p + 8*kgrp + e, t = 2047 - t'
        int tb = 2040 - t0p - 8 * kgrp;   // ascending base; e ↔ tb + (7-e)
        float4 ka = *(const float4*)(pk + tb);
        float4 kb = *(const float4*)(pk + tb + 4);
        float4 va = *(const float4*)(pv + tb);
        float4 vb = *(const float4*)(pv + tb + 4);
        float p0 = kb.w * vb.w;   // e=0
        float p1 = kb.z * vb.z;
        float p2 = kb.y * vb.y;
        float p3 = kb.x * vb.x;
        float p4 = ka.w * va.w;
        float p5 = ka.z * va.z;
        float p6 = ka.y * va.y;
        float p7 = ka.x * va.x;   // e=7
        int4 ai;
        ai.x = cvt_pk_bf16(p0, p1);
        ai.y = cvt_pk_bf16(p2, p3);
        ai.z = cvt_pk_bf16(p4, p5);
        ai.w = cvt_pk_bf16(p6, p7);
        bf16x8 afrag = __builtin_bit_cast(bf16x8, ai);

        int msv = (2128 - t0p - 16 * w) >> 7;
        msv = msv < 0 ? 0 : msv;
        int ms = __builtin_amdgcn_readfirstlane(msv);
        int base = idx0 + t0p;

#pragma unroll
        for (int m = 0; m < 16; ++m) {
            if (m >= ms) {
                int bi = base + (m << 7);
                float b0 = Kpad[bi + 0], b1 = Kpad[bi + 1];
                float b2 = Kpad[bi + 2], b3 = Kpad[bi + 3];
                float b4 = Kpad[bi + 4], b5 = Kpad[bi + 5];
                float b6 = Kpad[bi + 6], b7 = Kpad[bi + 7];
                int4 bi4;
                bi4.x = cvt_pk_bf16(b0, b1);
                bi4.y = cvt_pk_bf16(b2, b3);
                bi4.z = cvt_pk_bf16(b4, b5);
                bi4.w = cvt_pk_bf16(b6, b7);
                bf16x8 bfrag = __builtin_bit_cast(bf16x8, bi4);
                acc[m] = __builtin_amdgcn_mfma_f32_16x16x32_bf16(
                    afrag, bfrag, acc[m], 0, 0, 0);
            }
        }
    }

    // ---- epilogue: D-skip + q-gating.  C layout: col = lane&15 = l-offset,
    // row = (lane>>4)*4 + r  ->  d1 = lane>>4 (g), d2 = r.
    int g = lane >> 4;
    float Dh = Dv[hh];
    const float* qrow = q    + ((size_t)b * DM + hh * 4 + g) * LL;
    const float* krow = knew + ((size_t)b * DM + hh * 4 + g) * LL;
    const float* vb0  = v    + ((size_t)b * DM + hh * 4) * LL;
#pragma unroll
    for (int m = 0; m < 16; ++m) {
        int lm = 16 * w + 128 * m + n;
        float qv = qrow[lm];
        float kl = krow[lm];
        float vl0 = vb0[lm];
        float vl1 = vb0[(size_t)1 * LL + lm];
        float vl2 = vb0[(size_t)2 * LL + lm];
        float vl3 = vb0[(size_t)3 * LL + lm];
        float part0 = qv * (acc[m][0] + kl * vl0 * Dh);
        float part1 = qv * (acc[m][1] + kl * vl1 * Dh);
        float part2 = qv * (acc[m][2] + kl * vl2 * Dh);
        float part3 = qv * (acc[m][3] + kl * vl3 * Dh);
        part0 += __shfl_xor(part0, 16, 64); part0 += __shfl_xor(part0, 32, 64);
        part1 += __shfl_xor(part1, 16, 64); part1 += __shfl_xor(part1, 32, 64);
        part2 += __shfl_xor(part2, 16, 64); part2 += __shfl_xor(part2, 32, 64);
        part3 += __shfl_xor(part3, 16, 64); part3 += __shfl_xor(part3, 32, 64);
        float outv = (g == 0) ? part0 : (g == 1) ? part1 : (g == 2) ? part2 : part3;
        y_g[((size_t)b * DM + (size_t)g * 256 + hh) * LL + lm] = outv;
    }
}

// ---------------------------------------------------------------------------
extern "C" void kernel_launch(void* const* d_in, const int* in_sizes, int n_in,
                              void* d_out, int out_size, void* d_ws, size_t ws_size,
                              hipStream_t stream) {
    const float* u       = (const float*)d_in[0];
    const float* q_w     = (const float*)d_in[1];
    const float* q_b     = (const float*)d_in[2];
    const float* k_w     = (const float*)d_in[3];
    const float* k_b     = (const float*)d_in[4];
    const float* v_w     = (const float*)d_in[5];
    const float* v_b     = (const float*)d_in[6];
    const float* kern_k  = (const float*)d_in[7];
    const float* kern_v  = (const float*)d_in[8];
    const float* D_key   = (const float*)d_in[9];
    const float* D_v     = (const float*)d_in[10];
    const float* pw_w    = (const float*)d_in[11];
    const float* pw_b    = (const float*)d_in[12];
    float* out = (float*)d_out;

    const size_t BDL = (size_t)B_ * DM * LL;
    char* p = (char*)d_ws;
    float*          w_kv   = (float*)p;          p += (size_t)HH * LL * 4;
    unsigned short* w_kkey = (unsigned short*)p; p += (size_t)DM * LL * 2;
    unsigned short* w_wbuf = (unsigned short*)p; p += (size_t)DM * DM * 2;
    float*          w_R0   = (float*)p;          p += BDL * 4;
    float*          w_q    = (float*)p;          p += BDL * 4;
    float*          w_ky   = (float*)p;          p += BDL * 4;
    float*          w_v    = (float*)p;          p += BDL * 4;
    unsigned short* w_uT   = (unsigned short*)w_R0;
    unsigned short* w_ygT  = (unsigned short*)w_R0;
    float*          w_knew = w_R0;
    float*          w_yg   = w_ky;

    // 1. build kernels
    build_kernels_kernel<<<DM + HH, 256, 0, stream>>>(kern_k, kern_v, w_kkey, w_kv);

    // 2. u -> u_T bf16
    dim3 tgrid(LL / 64, DM / 64, B_);
    transpose_cvt_kernel<<<tgrid, 256, 0, stream>>>(u, w_uT, 0);

    // 3. projections (bf16 MFMA)
    dim3 ggrid(B_ * (LL / 128), DM / 128);
    wcvt_kernel<<<DM * DM / 1024, 256, 0, stream>>>(q_w, w_wbuf);
    gemm_mfma_kernel<<<ggrid, 256, 0, stream>>>(w_wbuf, w_uT, q_b, w_q);
    wcvt_kernel<<<DM * DM / 1024, 256, 0, stream>>>(k_w, w_wbuf);
    gemm_mfma_kernel<<<ggrid, 256, 0, stream>>>(w_wbuf, w_uT, k_b, w_ky);
    wcvt_kernel<<<DM * DM / 1024, 256, 0, stream>>>(v_w, w_wbuf);
    gemm_mfma_kernel<<<ggrid, 256, 0, stream>>>(w_wbuf, w_uT, v_b, w_v);

    // 4. key conv + skip (u_T dead; knew takes over R0)
    key_conv_kernel<<<DM * 8, 256, 0, stream>>>(w_ky, w_kkey, D_key, w_knew);

    // 5. value conv + gating via Toeplitz MFMA (y_g overwrites kraw)
    value_conv_mfma_kernel<<<B_ * HH, 512, 0, stream>>>(
        w_knew, w_v, w_q, w_kv, D_v, w_yg);

    // 6. y_g -> gelu -> yg_T bf16
    transpose_cvt_kernel<<<tgrid, 256, 0, stream>>>(w_yg, w_ygT, 1);

    // 7. pointwise projection
    wcvt_kernel<<<DM * DM / 1024, 256, 0, stream>>>(pw_w, w_wbuf);
    gemm_mfma_kernel<<<ggrid, 256, 0, stream>>>(w_wbuf, w_ygT, pw_b, out);
}

// Round 6
// 628.229 us; speedup vs baseline: 6.0934x; 1.6687x over previous
//
#include <hip/hip_runtime.h>
#include <cmath>

#define B_  4
#define DM  1024
#define LL  2048
#define HH  256

typedef short bf16x8 __attribute__((ext_vector_type(8)));
typedef float f32x4 __attribute__((ext_vector_type(4)));

__device__ __forceinline__ float gelu_exact(float x) {
    return x * 0.5f * (1.0f + erff(x * 0.70710678118654752f));
}
__device__ __forceinline__ unsigned short f2b(float f) {
    unsigned int x = __float_as_uint(f);
    unsigned int r = x + 0x7FFFu + ((x >> 16) & 1u);
    return (unsigned short)(r >> 16);
}
__device__ __forceinline__ float b2f(unsigned short u) {
    return __uint_as_float(((unsigned int)u) << 16);
}
__device__ __forceinline__ int cvt_pk_bf16(float lo, float hi) {
    int r;
    asm("v_cvt_pk_bf16_f32 %0, %1, %2" : "=v"(r) : "v"(lo), "v"(hi));
    return r;
}

// ---------------------------------------------------------------------------
// Kernel 1: build k_key (1024 x 2048, bf16) and k_v (256 x 2048, f32)
// ---------------------------------------------------------------------------
__global__ __launch_bounds__(256) void build_kernels_kernel(
        const float* __restrict__ src_key,   // (6, 1024, 64)
        const float* __restrict__ src_v,     // (6, 256, 64)
        unsigned short* __restrict__ k_key,  // (1024, 2048) bf16
        float* __restrict__ k_v) {           // (256, 2048) f32
    int bid = blockIdx.x;
    const float* src;
    int chanstride;
    bool is_key = bid < DM;
    if (is_key) {
        src = src_key + (size_t)bid * 64;
        chanstride = DM * 64;
    } else {
        src = src_v + (size_t)(bid - DM) * 64;
        chanstride = HH * 64;
    }
    int t = threadIdx.x;
    float vals[8];
    float ss = 0.0f;
#pragma unroll
    for (int r = 0; r < 8; ++r) {
        int j = r * 256 + t;
        int i, start, scale;
        if (j < 64)        { i = 0; start = 0;    scale = 1;  }
        else if (j < 128)  { i = 1; start = 64;   scale = 1;  }
        else if (j < 256)  { i = 2; start = 128;  scale = 2;  }
        else if (j < 512)  { i = 3; start = 256;  scale = 4;  }
        else if (j < 1024) { i = 4; start = 512;  scale = 8;  }
        else               { i = 5; start = 1024; scale = 16; }
        int jj = j - start;
        float pos = ((float)jj + 0.5f) / (float)scale - 0.5f;
        pos = fminf(fmaxf(pos, 0.0f), 63.0f);
        int lo = (int)pos;
        int hi = min(lo + 1, 63);
        float w = pos - (float)lo;
        const float* s = src + (size_t)i * chanstride;
        float x0 = s[lo], x1 = s[hi];
        float mult = (float)(1 << (5 - i));
        float vv = (x0 * (1.0f - w) + x1 * w) * mult;
        vals[r] = vv;
        ss += vv * vv;
    }
#pragma unroll
    for (int off = 32; off > 0; off >>= 1) ss += __shfl_down(ss, off, 64);
    __shared__ float red[4];
    __shared__ float norm_s;
    if ((t & 63) == 0) red[t >> 6] = ss;
    __syncthreads();
    if (t == 0) norm_s = sqrtf(red[0] + red[1] + red[2] + red[3]);
    __syncthreads();
    float nrm = norm_s;
    if (is_key) {
        unsigned short* dst = k_key + (size_t)bid * LL;
#pragma unroll
        for (int r = 0; r < 8; ++r) dst[r * 256 + t] = f2b(vals[r] / nrm);
    } else {
        float* dst = k_v + (size_t)(bid - DM) * LL;
#pragma unroll
        for (int r = 0; r < 8; ++r) dst[r * 256 + t] = vals[r] / nrm;
    }
}

// ---------------------------------------------------------------------------
// Kernel 2a: W f32 (1024x1024) -> bf16
// ---------------------------------------------------------------------------
__global__ __launch_bounds__(256) void wcvt_kernel(
        const float* __restrict__ src, unsigned short* __restrict__ dst) {
    int i = (blockIdx.x * 256 + threadIdx.x) * 4;
    float4 x = *(const float4*)(src + i);
    ushort4 o;
    o.x = f2b(x.x); o.y = f2b(x.y); o.z = f2b(x.z); o.w = f2b(x.w);
    *(ushort4*)(dst + i) = o;
}

// ---------------------------------------------------------------------------
// Kernel 2b: transpose+convert: src (B,1024,2048) f32 -> dst (B,2048,1024) bf16
// ---------------------------------------------------------------------------
__global__ __launch_bounds__(256) void transpose_cvt_kernel(
        const float* __restrict__ src, unsigned short* __restrict__ dst,
        int do_gelu) {
    __shared__ float tile[64][65];
    int l0 = blockIdx.x << 6;
    int h0 = blockIdx.y << 6;
    int b  = blockIdx.z;
    int t = threadIdx.x;
    int r = t >> 4, c4 = (t & 15) << 2;
    const float* s = src + ((size_t)b * DM + h0) * LL + l0;
#pragma unroll
    for (int p = 0; p < 4; ++p) {
        float4 x = *(const float4*)(s + (size_t)(p * 16 + r) * LL + c4);
        tile[p * 16 + r][c4 + 0] = x.x;
        tile[p * 16 + r][c4 + 1] = x.y;
        tile[p * 16 + r][c4 + 2] = x.z;
        tile[p * 16 + r][c4 + 3] = x.w;
    }
    __syncthreads();
    unsigned short* d = dst + ((size_t)b * LL + l0) * DM + h0;
#pragma unroll
    for (int p = 0; p < 4; ++p) {
        int lr = p * 16 + r;
        float x0 = tile[c4 + 0][lr];
        float x1 = tile[c4 + 1][lr];
        float x2 = tile[c4 + 2][lr];
        float x3 = tile[c4 + 3][lr];
        if (do_gelu) {
            x0 = gelu_exact(x0); x1 = gelu_exact(x1);
            x2 = gelu_exact(x2); x3 = gelu_exact(x3);
        }
        ushort4 o;
        o.x = f2b(x0); o.y = f2b(x1); o.z = f2b(x2); o.w = f2b(x3);
        *(ushort4*)(d + (size_t)lr * DM + c4) = o;
    }
}

// ---------------------------------------------------------------------------
// Kernel 3: MFMA GEMM.  C[b,o,l] = bias[o] + sum_h A[o,h] * Ubf[b,l,h]
// ---------------------------------------------------------------------------
__global__ __launch_bounds__(256) void gemm_mfma_kernel(
        const unsigned short* __restrict__ A,
        const unsigned short* __restrict__ Ubf,
        const float* __restrict__ bias,
        float* __restrict__ C) {
    __shared__ unsigned short As[128 * 64];
    __shared__ unsigned short Bs[128 * 64];
    int bidx = blockIdx.x;
    int b = bidx >> 4;
    int n0 = (bidx & 15) << 7;
    int m0 = blockIdx.y << 7;
    int t = threadIdx.x;
    int lane = t & 63, wave = t >> 6;
    int wr = wave >> 1, wc = wave & 1;

    const unsigned short* Ub = Ubf + (size_t)b * LL * DM;

    f32x4 acc[4][4];
#pragma unroll
    for (int i = 0; i < 4; ++i)
#pragma unroll
        for (int j = 0; j < 4; ++j) {
            f32x4 z = {0.0f, 0.0f, 0.0f, 0.0f};
            acc[i][j] = z;
        }

    int srow = t >> 3;
    int scol = (t & 7) << 3;
    int lrow = lane & 15;
    int lk = (lane >> 4) << 3;

    for (int k0 = 0; k0 < DM; k0 += 64) {
        __syncthreads();
#pragma unroll
        for (int p = 0; p < 4; ++p) {
            int row = p * 32 + srow;
            uint4 av = *(const uint4*)(A  + (size_t)(m0 + row) * DM + k0 + scol);
            uint4 bv = *(const uint4*)(Ub + (size_t)(n0 + row) * DM + k0 + scol);
            *(uint4*)&As[row * 64 + scol] = av;
            *(uint4*)&Bs[row * 64 + scol] = bv;
        }
        __syncthreads();
#pragma unroll
        for (int kk = 0; kk < 64; kk += 32) {
            bf16x8 af[4], bfr[4];
#pragma unroll
            for (int mi = 0; mi < 4; ++mi)
                af[mi] = *(const bf16x8*)&As[(wr * 64 + mi * 16 + lrow) * 64 + kk + lk];
#pragma unroll
            for (int ni = 0; ni < 4; ++ni)
                bfr[ni] = *(const bf16x8*)&Bs[(wc * 64 + ni * 16 + lrow) * 64 + kk + lk];
#pragma unroll
            for (int mi = 0; mi < 4; ++mi)
#pragma unroll
                for (int ni = 0; ni < 4; ++ni)
                    acc[mi][ni] = __builtin_amdgcn_mfma_f32_16x16x32_bf16(
                        af[mi], bfr[ni], acc[mi][ni], 0, 0, 0);
        }
    }
    int rg = (lane >> 4) << 2;
    int cn = lane & 15;
#pragma unroll
    for (int mi = 0; mi < 4; ++mi) {
#pragma unroll
        for (int r = 0; r < 4; ++r) {
            int o = m0 + wr * 64 + mi * 16 + rg + r;
            float bo = bias[o];
            float* crow = C + ((size_t)b * DM + o) * LL + n0 + wc * 64;
#pragma unroll
            for (int ni = 0; ni < 4; ++ni)
                crow[ni * 16 + cn] = acc[mi][ni][r] + bo;
        }
    }
}

// ---------------------------------------------------------------------------
// Kernel 4: key-side causal conv + skip via Toeplitz MFMA.
// Per block (channel c): y[b=4][l=2048] = sum_{t'} kkr[b,t'] * Kpad[l+t'-1999]
// with kkr[b,t'] = kk_raw[b,c,2047-t'] (reversed), Kpad[j] = (j>=48)?K[c][j-48]:0.
// Same geometry as value_conv_mfma (verified): 8 waves, wave w owns l-tiles
// l0 = 16w + 128m, m=0..15; A rows 4..15 are zero (lane mask n<4).
// Epilogue (g==0 lanes): knew = conv + kk*D_key.
// ---------------------------------------------------------------------------
__global__ __launch_bounds__(512) void key_conv_mfma_kernel(
        const float* __restrict__ kk_raw,        // (B, 1024, 2048)
        const unsigned short* __restrict__ k_key,// (1024, 2048) bf16
        const float* __restrict__ D_key,         // (1024)
        float* __restrict__ knew) {              // (B, 1024, 2048)
    __shared__ float Kpad[2096];
    int c = blockIdx.x;
    int tid = threadIdx.x;

    const unsigned short* kp = k_key + (size_t)c * LL;
    for (int j = tid; j < 2096; j += 512)
        Kpad[j] = (j >= 48) ? b2f(kp[j - 48]) : 0.0f;
    __syncthreads();

    int w = tid >> 6, lane = tid & 63;
    int n = lane & 15, kgrp = lane >> 4;
    float zmask = (n < 4) ? 1.0f : 0.0f;
    int brow = (n < 4) ? n : 0;
    const float* pk = kk_raw + ((size_t)brow * DM + c) * LL;

    f32x4 acc[16];
#pragma unroll
    for (int m = 0; m < 16; ++m) {
        f32x4 z = {0.0f, 0.0f, 0.0f, 0.0f};
        acc[m] = z;
    }

    int idx0 = 16 * w + n + 8 * kgrp - 1999;

    for (int s = 0; s < 64; ++s) {
        int t0p = s << 5;
        int tb = 2040 - t0p - 8 * kgrp;   // e <-> tb + (7-e)
        float4 ka = *(const float4*)(pk + tb);
        float4 kb = *(const float4*)(pk + tb + 4);
        float p0 = kb.w * zmask;   // e=0
        float p1 = kb.z * zmask;
        float p2 = kb.y * zmask;
        float p3 = kb.x * zmask;
        float p4 = ka.w * zmask;
        float p5 = ka.z * zmask;
        float p6 = ka.y * zmask;
        float p7 = ka.x * zmask;   // e=7
        int4 ai;
        ai.x = cvt_pk_bf16(p0, p1);
        ai.y = cvt_pk_bf16(p2, p3);
        ai.z = cvt_pk_bf16(p4, p5);
        ai.w = cvt_pk_bf16(p6, p7);
        bf16x8 afrag = __builtin_bit_cast(bf16x8, ai);

        int msv = (2128 - t0p - 16 * w) >> 7;
        msv = msv < 0 ? 0 : msv;
        int ms = __builtin_amdgcn_readfirstlane(msv);
        int base = idx0 + t0p;

#pragma unroll
        for (int m = 0; m < 16; ++m) {
            if (m >= ms) {
                int bi = base + (m << 7);
                float b0 = Kpad[bi + 0], b1 = Kpad[bi + 1];
                float b2 = Kpad[bi + 2], b3 = Kpad[bi + 3];
                float b4 = Kpad[bi + 4], b5 = Kpad[bi + 5];
                float b6 = Kpad[bi + 6], b7 = Kpad[bi + 7];
                int4 bi4;
                bi4.x = cvt_pk_bf16(b0, b1);
                bi4.y = cvt_pk_bf16(b2, b3);
                bi4.z = cvt_pk_bf16(b4, b5);
                bi4.w = cvt_pk_bf16(b6, b7);
                bf16x8 bfrag = __builtin_bit_cast(bf16x8, bi4);
                acc[m] = __builtin_amdgcn_mfma_f32_16x16x32_bf16(
                    afrag, bfrag, acc[m], 0, 0, 0);
            }
        }
    }

    // epilogue: rows 0-3 live in g==0 lanes, reg index = b. D_key skip fused.
    int g = lane >> 4;
    if (g == 0) {
        float dk = D_key[c];
#pragma unroll
        for (int m = 0; m < 16; ++m) {
            int lm = 16 * w + 128 * m + n;
#pragma unroll
            for (int b = 0; b < 4; ++b) {
                size_t off = ((size_t)b * DM + c) * LL + lm;
                knew[off] = acc[m][b] + kk_raw[off] * dk;
            }
        }
    }
}

// ---------------------------------------------------------------------------
// Kernel 5: value-side gated conv via Toeplitz MFMA (verified round 5).
// ---------------------------------------------------------------------------
__global__ __launch_bounds__(512) void value_conv_mfma_kernel(
        const float* __restrict__ knew,  // (B, 1024, 2048)
        const float* __restrict__ v,     // (B, 1024, 2048)
        const float* __restrict__ q,     // (B, 1024, 2048)
        const float* __restrict__ k_v,   // (256, 2048) f32
        const float* __restrict__ Dv,    // (256)
        float* __restrict__ y_g) {       // (B, 1024, 2048), channel = d2*256+hh
    __shared__ float Kpad[2096];
    int bid = blockIdx.x;
    int hh = bid & 255, b = bid >> 8;
    int tid = threadIdx.x;

    const float* kvp = k_v + (size_t)hh * LL;
    for (int j = tid; j < 2096; j += 512)
        Kpad[j] = (j >= 48) ? kvp[j - 48] : 0.0f;
    __syncthreads();

    int w = tid >> 6, lane = tid & 63;
    int n = lane & 15, kgrp = lane >> 4;
    int d1a = n >> 2, d2a = n & 3;

    const float* pk = knew + ((size_t)b * DM + hh * 4 + d1a) * LL;
    const float* pv = v    + ((size_t)b * DM + hh * 4 + d2a) * LL;

    f32x4 acc[16];
#pragma unroll
    for (int m = 0; m < 16; ++m) {
        f32x4 z = {0.0f, 0.0f, 0.0f, 0.0f};
        acc[m] = z;
    }

    int idx0 = 16 * w + n + 8 * kgrp - 1999;

    for (int s = 0; s < 64; ++s) {
        int t0p = s << 5;
        int tb = 2040 - t0p - 8 * kgrp;
        float4 ka = *(const float4*)(pk + tb);
        float4 kb = *(const float4*)(pk + tb + 4);
        float4 va = *(const float4*)(pv + tb);
        float4 vb = *(const float4*)(pv + tb + 4);
        float p0 = kb.w * vb.w;
        float p1 = kb.z * vb.z;
        float p2 = kb.y * vb.y;
        float p3 = kb.x * vb.x;
        float p4 = ka.w * va.w;
        float p5 = ka.z * va.z;
        float p6 = ka.y * va.y;
        float p7 = ka.x * va.x;
        int4 ai;
        ai.x = cvt_pk_bf16(p0, p1);
        ai.y = cvt_pk_bf16(p2, p3);
        ai.z = cvt_pk_bf16(p4, p5);
        ai.w = cvt_pk_bf16(p6, p7);
        bf16x8 afrag = __builtin_bit_cast(bf16x8, ai);

        int msv = (2128 - t0p - 16 * w) >> 7;
        msv = msv < 0 ? 0 : msv;
        int ms = __builtin_amdgcn_readfirstlane(msv);
        int base = idx0 + t0p;

#pragma unroll
        for (int m = 0; m < 16; ++m) {
            if (m >= ms) {
                int bi = base + (m << 7);
                float b0 = Kpad[bi + 0], b1 = Kpad[bi + 1];
                float b2 = Kpad[bi + 2], b3 = Kpad[bi + 3];
                float b4 = Kpad[bi + 4], b5 = Kpad[bi + 5];
                float b6 = Kpad[bi + 6], b7 = Kpad[bi + 7];
                int4 bi4;
                bi4.x = cvt_pk_bf16(b0, b1);
                bi4.y = cvt_pk_bf16(b2, b3);
                bi4.z = cvt_pk_bf16(b4, b5);
                bi4.w = cvt_pk_bf16(b6, b7);
                bf16x8 bfrag = __builtin_bit_cast(bf16x8, bi4);
                acc[m] = __builtin_amdgcn_mfma_f32_16x16x32_bf16(
                    afrag, bfrag, acc[m], 0, 0, 0);
            }
        }
    }

    int g = lane >> 4;
    float Dh = Dv[hh];
    const float* qrow = q    + ((size_t)b * DM + hh * 4 + g) * LL;
    const float* krow = knew + ((size_t)b * DM + hh * 4 + g) * LL;
    const float* vb0  = v    + ((size_t)b * DM + hh * 4) * LL;
#pragma unroll
    for (int m = 0; m < 16; ++m) {
        int lm = 16 * w + 128 * m + n;
        float qv = qrow[lm];
        float kl = krow[lm];
        float vl0 = vb0[lm];
        float vl1 = vb0[(size_t)1 * LL + lm];
        float vl2 = vb0[(size_t)2 * LL + lm];
        float vl3 = vb0[(size_t)3 * LL + lm];
        float part0 = qv * (acc[m][0] + kl * vl0 * Dh);
        float part1 = qv * (acc[m][1] + kl * vl1 * Dh);
        float part2 = qv * (acc[m][2] + kl * vl2 * Dh);
        float part3 = qv * (acc[m][3] + kl * vl3 * Dh);
        part0 += __shfl_xor(part0, 16, 64); part0 += __shfl_xor(part0, 32, 64);
        part1 += __shfl_xor(part1, 16, 64); part1 += __shfl_xor(part1, 32, 64);
        part2 += __shfl_xor(part2, 16, 64); part2 += __shfl_xor(part2, 32, 64);
        part3 += __shfl_xor(part3, 16, 64); part3 += __shfl_xor(part3, 32, 64);
        float outv = (g == 0) ? part0 : (g == 1) ? part1 : (g == 2) ? part2 : part3;
        y_g[((size_t)b * DM + (size_t)g * 256 + hh) * LL + lm] = outv;
    }
}

// ---------------------------------------------------------------------------
extern "C" void kernel_launch(void* const* d_in, const int* in_sizes, int n_in,
                              void* d_out, int out_size, void* d_ws, size_t ws_size,
                              hipStream_t stream) {
    const float* u       = (const float*)d_in[0];
    const float* q_w     = (const float*)d_in[1];
    const float* q_b     = (const float*)d_in[2];
    const float* k_w     = (const float*)d_in[3];
    const float* k_b     = (const float*)d_in[4];
    const float* v_w     = (const float*)d_in[5];
    const float* v_b     = (const float*)d_in[6];
    const float* kern_k  = (const float*)d_in[7];
    const float* kern_v  = (const float*)d_in[8];
    const float* D_key   = (const float*)d_in[9];
    const float* D_v     = (const float*)d_in[10];
    const float* pw_w    = (const float*)d_in[11];
    const float* pw_b    = (const float*)d_in[12];
    float* out = (float*)d_out;

    const size_t BDL = (size_t)B_ * DM * LL;
    char* p = (char*)d_ws;
    float*          w_kv   = (float*)p;          p += (size_t)HH * LL * 4;
    unsigned short* w_kkey = (unsigned short*)p; p += (size_t)DM * LL * 2;
    unsigned short* w_wbuf = (unsigned short*)p; p += (size_t)DM * DM * 2;
    float*          w_R0   = (float*)p;          p += BDL * 4;
    float*          w_q    = (float*)p;          p += BDL * 4;
    float*          w_ky   = (float*)p;          p += BDL * 4;
    float*          w_v    = (float*)p;          p += BDL * 4;
    unsigned short* w_uT   = (unsigned short*)w_R0;
    unsigned short* w_ygT  = (unsigned short*)w_R0;
    float*          w_knew = w_R0;
    float*          w_yg   = w_ky;

    // 1. build kernels
    build_kernels_kernel<<<DM + HH, 256, 0, stream>>>(kern_k, kern_v, w_kkey, w_kv);

    // 2. u -> u_T bf16
    dim3 tgrid(LL / 64, DM / 64, B_);
    transpose_cvt_kernel<<<tgrid, 256, 0, stream>>>(u, w_uT, 0);

    // 3. projections (bf16 MFMA)
    dim3 ggrid(B_ * (LL / 128), DM / 128);
    wcvt_kernel<<<DM * DM / 1024, 256, 0, stream>>>(q_w, w_wbuf);
    gemm_mfma_kernel<<<ggrid, 256, 0, stream>>>(w_wbuf, w_uT, q_b, w_q);
    wcvt_kernel<<<DM * DM / 1024, 256, 0, stream>>>(k_w, w_wbuf);
    gemm_mfma_kernel<<<ggrid, 256, 0, stream>>>(w_wbuf, w_uT, k_b, w_ky);
    wcvt_kernel<<<DM * DM / 1024, 256, 0, stream>>>(v_w, w_wbuf);
    gemm_mfma_kernel<<<ggrid, 256, 0, stream>>>(w_wbuf, w_uT, v_b, w_v);

    // 4. key conv + skip via Toeplitz MFMA (u_T dead; knew takes over R0)
    key_conv_mfma_kernel<<<DM, 512, 0, stream>>>(w_ky, w_kkey, D_key, w_knew);

    // 5. value conv + gating via Toeplitz MFMA (y_g overwrites kraw)
    value_conv_mfma_kernel<<<B_ * HH, 512, 0, stream>>>(
        w_knew, w_v, w_q, w_kv, D_v, w_yg);

    // 6. y_g -> gelu -> yg_T bf16
    transpose_cvt_kernel<<<tgrid, 256, 0, stream>>>(w_yg, w_ygT, 1);

    // 7. pointwise projection
    wcvt_kernel<<<DM * DM / 1024, 256, 0, stream>>>(pw_w, w_wbuf);
    gemm_mfma_kernel<<<ggrid, 256, 0, stream>>>(w_wbuf, w_ygT, pw_b, out);
}

// Round 7
// 567.418 us; speedup vs baseline: 6.7464x; 1.1072x over previous
//
#include <hip/hip_runtime.h>
#include <cmath>

#define B_  4
#define DM  1024
#define LL  2048
#define HH  256

#define KBSTRIDE 2120   // bf16 elems per shifted copy (stride chosen: dwords%32==4)

typedef short bf16x8 __attribute__((ext_vector_type(8)));
typedef float f32x4 __attribute__((ext_vector_type(4)));

__device__ __forceinline__ float gelu_exact(float x) {
    return x * 0.5f * (1.0f + erff(x * 0.70710678118654752f));
}
__device__ __forceinline__ unsigned short f2b(float f) {
    unsigned int x = __float_as_uint(f);
    unsigned int r = x + 0x7FFFu + ((x >> 16) & 1u);
    return (unsigned short)(r >> 16);
}
__device__ __forceinline__ float b2f(unsigned short u) {
    return __uint_as_float(((unsigned int)u) << 16);
}
__device__ __forceinline__ int cvt_pk_bf16(float lo, float hi) {
    int r;
    asm("v_cvt_pk_bf16_f32 %0, %1, %2" : "=v"(r) : "v"(lo), "v"(hi));
    return r;
}

// ---------------------------------------------------------------------------
// Kernel 1: build k_key (1024 x 2048, bf16) and k_v (256 x 2048, f32)
// ---------------------------------------------------------------------------
__global__ __launch_bounds__(256) void build_kernels_kernel(
        const float* __restrict__ src_key,   // (6, 1024, 64)
        const float* __restrict__ src_v,     // (6, 256, 64)
        unsigned short* __restrict__ k_key,  // (1024, 2048) bf16
        float* __restrict__ k_v) {           // (256, 2048) f32
    int bid = blockIdx.x;
    const float* src;
    int chanstride;
    bool is_key = bid < DM;
    if (is_key) {
        src = src_key + (size_t)bid * 64;
        chanstride = DM * 64;
    } else {
        src = src_v + (size_t)(bid - DM) * 64;
        chanstride = HH * 64;
    }
    int t = threadIdx.x;
    float vals[8];
    float ss = 0.0f;
#pragma unroll
    for (int r = 0; r < 8; ++r) {
        int j = r * 256 + t;
        int i, start, scale;
        if (j < 64)        { i = 0; start = 0;    scale = 1;  }
        else if (j < 128)  { i = 1; start = 64;   scale = 1;  }
        else if (j < 256)  { i = 2; start = 128;  scale = 2;  }
        else if (j < 512)  { i = 3; start = 256;  scale = 4;  }
        else if (j < 1024) { i = 4; start = 512;  scale = 8;  }
        else               { i = 5; start = 1024; scale = 16; }
        int jj = j - start;
        float pos = ((float)jj + 0.5f) / (float)scale - 0.5f;
        pos = fminf(fmaxf(pos, 0.0f), 63.0f);
        int lo = (int)pos;
        int hi = min(lo + 1, 63);
        float w = pos - (float)lo;
        const float* s = src + (size_t)i * chanstride;
        float x0 = s[lo], x1 = s[hi];
        float mult = (float)(1 << (5 - i));
        float vv = (x0 * (1.0f - w) + x1 * w) * mult;
        vals[r] = vv;
        ss += vv * vv;
    }
#pragma unroll
    for (int off = 32; off > 0; off >>= 1) ss += __shfl_down(ss, off, 64);
    __shared__ float red[4];
    __shared__ float norm_s;
    if ((t & 63) == 0) red[t >> 6] = ss;
    __syncthreads();
    if (t == 0) norm_s = sqrtf(red[0] + red[1] + red[2] + red[3]);
    __syncthreads();
    float nrm = norm_s;
    if (is_key) {
        unsigned short* dst = k_key + (size_t)bid * LL;
#pragma unroll
        for (int r = 0; r < 8; ++r) dst[r * 256 + t] = f2b(vals[r] / nrm);
    } else {
        float* dst = k_v + (size_t)(bid - DM) * LL;
#pragma unroll
        for (int r = 0; r < 8; ++r) dst[r * 256 + t] = vals[r] / nrm;
    }
}

// ---------------------------------------------------------------------------
// Kernel 2a: W f32 (1024x1024) -> bf16
// ---------------------------------------------------------------------------
__global__ __launch_bounds__(256) void wcvt_kernel(
        const float* __restrict__ src, unsigned short* __restrict__ dst) {
    int i = (blockIdx.x * 256 + threadIdx.x) * 4;
    float4 x = *(const float4*)(src + i);
    ushort4 o;
    o.x = f2b(x.x); o.y = f2b(x.y); o.z = f2b(x.z); o.w = f2b(x.w);
    *(ushort4*)(dst + i) = o;
}

// ---------------------------------------------------------------------------
// Kernel 2b: transpose+convert: src (B,1024,2048) f32 -> dst (B,2048,1024) bf16
// ---------------------------------------------------------------------------
__global__ __launch_bounds__(256) void transpose_cvt_kernel(
        const float* __restrict__ src, unsigned short* __restrict__ dst,
        int do_gelu) {
    __shared__ float tile[64][65];
    int l0 = blockIdx.x << 6;
    int h0 = blockIdx.y << 6;
    int b  = blockIdx.z;
    int t = threadIdx.x;
    int r = t >> 4, c4 = (t & 15) << 2;
    const float* s = src + ((size_t)b * DM + h0) * LL + l0;
#pragma unroll
    for (int p = 0; p < 4; ++p) {
        float4 x = *(const float4*)(s + (size_t)(p * 16 + r) * LL + c4);
        tile[p * 16 + r][c4 + 0] = x.x;
        tile[p * 16 + r][c4 + 1] = x.y;
        tile[p * 16 + r][c4 + 2] = x.z;
        tile[p * 16 + r][c4 + 3] = x.w;
    }
    __syncthreads();
    unsigned short* d = dst + ((size_t)b * LL + l0) * DM + h0;
#pragma unroll
    for (int p = 0; p < 4; ++p) {
        int lr = p * 16 + r;
        float x0 = tile[c4 + 0][lr];
        float x1 = tile[c4 + 1][lr];
        float x2 = tile[c4 + 2][lr];
        float x3 = tile[c4 + 3][lr];
        if (do_gelu) {
            x0 = gelu_exact(x0); x1 = gelu_exact(x1);
            x2 = gelu_exact(x2); x3 = gelu_exact(x3);
        }
        ushort4 o;
        o.x = f2b(x0); o.y = f2b(x1); o.z = f2b(x2); o.w = f2b(x3);
        *(ushort4*)(d + (size_t)lr * DM + c4) = o;
    }
}

// ---------------------------------------------------------------------------
// Kernel 3: MFMA GEMM.  C[b,o,l] = bias[o] + sum_h A[o,h] * Ubf[b,l,h]
// ---------------------------------------------------------------------------
__global__ __launch_bounds__(256) void gemm_mfma_kernel(
        const unsigned short* __restrict__ A,
        const unsigned short* __restrict__ Ubf,
        const float* __restrict__ bias,
        float* __restrict__ C) {
    __shared__ unsigned short As[128 * 64];
    __shared__ unsigned short Bs[128 * 64];
    int bidx = blockIdx.x;
    int b = bidx >> 4;
    int n0 = (bidx & 15) << 7;
    int m0 = blockIdx.y << 7;
    int t = threadIdx.x;
    int lane = t & 63, wave = t >> 6;
    int wr = wave >> 1, wc = wave & 1;

    const unsigned short* Ub = Ubf + (size_t)b * LL * DM;

    f32x4 acc[4][4];
#pragma unroll
    for (int i = 0; i < 4; ++i)
#pragma unroll
        for (int j = 0; j < 4; ++j) {
            f32x4 z = {0.0f, 0.0f, 0.0f, 0.0f};
            acc[i][j] = z;
        }

    int srow = t >> 3;
    int scol = (t & 7) << 3;
    int lrow = lane & 15;
    int lk = (lane >> 4) << 3;

    for (int k0 = 0; k0 < DM; k0 += 64) {
        __syncthreads();
#pragma unroll
        for (int p = 0; p < 4; ++p) {
            int row = p * 32 + srow;
            uint4 av = *(const uint4*)(A  + (size_t)(m0 + row) * DM + k0 + scol);
            uint4 bv = *(const uint4*)(Ub + (size_t)(n0 + row) * DM + k0 + scol);
            *(uint4*)&As[row * 64 + scol] = av;
            *(uint4*)&Bs[row * 64 + scol] = bv;
        }
        __syncthreads();
#pragma unroll
        for (int kk = 0; kk < 64; kk += 32) {
            bf16x8 af[4], bfr[4];
#pragma unroll
            for (int mi = 0; mi < 4; ++mi)
                af[mi] = *(const bf16x8*)&As[(wr * 64 + mi * 16 + lrow) * 64 + kk + lk];
#pragma unroll
            for (int ni = 0; ni < 4; ++ni)
                bfr[ni] = *(const bf16x8*)&Bs[(wc * 64 + ni * 16 + lrow) * 64 + kk + lk];
#pragma unroll
            for (int mi = 0; mi < 4; ++mi)
#pragma unroll
                for (int ni = 0; ni < 4; ++ni)
                    acc[mi][ni] = __builtin_amdgcn_mfma_f32_16x16x32_bf16(
                        af[mi], bfr[ni], acc[mi][ni], 0, 0, 0);
        }
    }
    int rg = (lane >> 4) << 2;
    int cn = lane & 15;
#pragma unroll
    for (int mi = 0; mi < 4; ++mi) {
#pragma unroll
        for (int r = 0; r < 4; ++r) {
            int o = m0 + wr * 64 + mi * 16 + rg + r;
            float bo = bias[o];
            float* crow = C + ((size_t)b * DM + o) * LL + n0 + wc * 64;
#pragma unroll
            for (int ni = 0; ni < 4; ++ni)
                crow[ni * 16 + cn] = acc[mi][ni][r] + bo;
        }
    }
}

// ---------------------------------------------------------------------------
// Kernel 4: key-side causal conv + skip via Toeplitz MFMA.
// B-fragment = single ds_read_b128 from 8 shifted bf16 copies:
// Kb[r][x] = Kpad[x+r]; lane r = (n+1)&7 (== bi mod 8, constant per lane);
// read at elem r*KBSTRIDE + (bi - r)  (16B aligned).
// ---------------------------------------------------------------------------
__global__ __launch_bounds__(512) void key_conv_mfma_kernel(
        const float* __restrict__ kk_raw,        // (B, 1024, 2048)
        const unsigned short* __restrict__ k_key,// (1024, 2048) bf16
        const float* __restrict__ D_key,         // (1024)
        float* __restrict__ knew) {              // (B, 1024, 2048)
    __shared__ unsigned short Kb[8 * KBSTRIDE];  // ~33.1 KB
    int c = blockIdx.x;
    int tid = threadIdx.x;

    const unsigned short* kp = k_key + (size_t)c * LL;
#pragma unroll
    for (int r = 0; r < 8; ++r) {
        for (int x = tid; x < 2096; x += 512) {
            int src = x + r - 48;   // Kpad[j] = K[j-48], zero-padded
            Kb[r * KBSTRIDE + x] =
                (src >= 0 && src < LL) ? kp[src] : (unsigned short)0;
        }
    }
    __syncthreads();

    int w = tid >> 6, lane = tid & 63;
    int n = lane & 15, kgrp = lane >> 4;
    float zmask = (n < 4) ? 1.0f : 0.0f;
    int brow = (n < 4) ? n : 0;
    const float* pk = kk_raw + ((size_t)brow * DM + c) * LL;

    f32x4 acc[16];
#pragma unroll
    for (int m = 0; m < 16; ++m) {
        f32x4 z = {0.0f, 0.0f, 0.0f, 0.0f};
        acc[m] = z;
    }

    int idx0 = 16 * w + n + 8 * kgrp - 1999;
    int rsh = (n + 1) & 7;                       // == idx0 mod 8
    int lbase = rsh * KBSTRIDE + (idx0 - rsh);   // elem base, 8-elem aligned

    for (int s = 0; s < 64; ++s) {
        int t0p = s << 5;
        int tb = 2040 - t0p - 8 * kgrp;   // e <-> tb + (7-e)
        float4 ka = *(const float4*)(pk + tb);
        float4 kb = *(const float4*)(pk + tb + 4);
        float p0 = kb.w * zmask;
        float p1 = kb.z * zmask;
        float p2 = kb.y * zmask;
        float p3 = kb.x * zmask;
        float p4 = ka.w * zmask;
        float p5 = ka.z * zmask;
        float p6 = ka.y * zmask;
        float p7 = ka.x * zmask;
        int4 ai;
        ai.x = cvt_pk_bf16(p0, p1);
        ai.y = cvt_pk_bf16(p2, p3);
        ai.z = cvt_pk_bf16(p4, p5);
        ai.w = cvt_pk_bf16(p6, p7);
        bf16x8 afrag = __builtin_bit_cast(bf16x8, ai);

        int msv = (2128 - t0p - 16 * w) >> 7;
        msv = msv < 0 ? 0 : msv;
        int ms = __builtin_amdgcn_readfirstlane(msv);
        const unsigned short* kbp = &Kb[lbase + t0p];

#pragma unroll
        for (int m = 0; m < 16; ++m) {
            if (m >= ms) {
                bf16x8 bfrag = *(const bf16x8*)(kbp + (m << 7));
                acc[m] = __builtin_amdgcn_mfma_f32_16x16x32_bf16(
                    afrag, bfrag, acc[m], 0, 0, 0);
            }
        }
    }

    int g = lane >> 4;
    if (g == 0) {
        float dk = D_key[c];
#pragma unroll
        for (int m = 0; m < 16; ++m) {
            int lm = 16 * w + 128 * m + n;
#pragma unroll
            for (int b = 0; b < 4; ++b) {
                size_t off = ((size_t)b * DM + c) * LL + lm;
                knew[off] = acc[m][b] + kk_raw[off] * dk;
            }
        }
    }
}

// ---------------------------------------------------------------------------
// Kernel 5: value-side gated conv via Toeplitz MFMA (same B-read scheme).
// ---------------------------------------------------------------------------
__global__ __launch_bounds__(512) void value_conv_mfma_kernel(
        const float* __restrict__ knew,  // (B, 1024, 2048)
        const float* __restrict__ v,     // (B, 1024, 2048)
        const float* __restrict__ q,     // (B, 1024, 2048)
        const float* __restrict__ k_v,   // (256, 2048) f32
        const float* __restrict__ Dv,    // (256)
        float* __restrict__ y_g) {       // (B, 1024, 2048), channel = d2*256+hh
    __shared__ unsigned short Kb[8 * KBSTRIDE];  // ~33.1 KB
    int bid = blockIdx.x;
    int hh = bid & 255, b = bid >> 8;
    int tid = threadIdx.x;

    const float* kvp = k_v + (size_t)hh * LL;
#pragma unroll
    for (int r = 0; r < 8; ++r) {
        for (int x = tid; x < 2096; x += 512) {
            int src = x + r - 48;
            Kb[r * KBSTRIDE + x] =
                (src >= 0 && src < LL) ? f2b(kvp[src]) : (unsigned short)0;
        }
    }
    __syncthreads();

    int w = tid >> 6, lane = tid & 63;
    int n = lane & 15, kgrp = lane >> 4;
    int d1a = n >> 2, d2a = n & 3;

    const float* pk = knew + ((size_t)b * DM + hh * 4 + d1a) * LL;
    const float* pv = v    + ((size_t)b * DM + hh * 4 + d2a) * LL;

    f32x4 acc[16];
#pragma unroll
    for (int m = 0; m < 16; ++m) {
        f32x4 z = {0.0f, 0.0f, 0.0f, 0.0f};
        acc[m] = z;
    }

    int idx0 = 16 * w + n + 8 * kgrp - 1999;
    int rsh = (n + 1) & 7;
    int lbase = rsh * KBSTRIDE + (idx0 - rsh);

    for (int s = 0; s < 64; ++s) {
        int t0p = s << 5;
        int tb = 2040 - t0p - 8 * kgrp;
        float4 ka = *(const float4*)(pk + tb);
        float4 kb = *(const float4*)(pk + tb + 4);
        float4 va = *(const float4*)(pv + tb);
        float4 vb = *(const float4*)(pv + tb + 4);
        float p0 = kb.w * vb.w;
        float p1 = kb.z * vb.z;
        float p2 = kb.y * vb.y;
        float p3 = kb.x * vb.x;
        float p4 = ka.w * va.w;
        float p5 = ka.z * va.z;
        float p6 = ka.y * va.y;
        float p7 = ka.x * va.x;
        int4 ai;
        ai.x = cvt_pk_bf16(p0, p1);
        ai.y = cvt_pk_bf16(p2, p3);
        ai.z = cvt_pk_bf16(p4, p5);
        ai.w = cvt_pk_bf16(p6, p7);
        bf16x8 afrag = __builtin_bit_cast(bf16x8, ai);

        int msv = (2128 - t0p - 16 * w) >> 7;
        msv = msv < 0 ? 0 : msv;
        int ms = __builtin_amdgcn_readfirstlane(msv);
        const unsigned short* kbp = &Kb[lbase + t0p];

#pragma unroll
        for (int m = 0; m < 16; ++m) {
            if (m >= ms) {
                bf16x8 bfrag = *(const bf16x8*)(kbp + (m << 7));
                acc[m] = __builtin_amdgcn_mfma_f32_16x16x32_bf16(
                    afrag, bfrag, acc[m], 0, 0, 0);
            }
        }
    }

    int g = lane >> 4;
    float Dh = Dv[hh];
    const float* qrow = q    + ((size_t)b * DM + hh * 4 + g) * LL;
    const float* krow = knew + ((size_t)b * DM + hh * 4 + g) * LL;
    const float* vb0  = v    + ((size_t)b * DM + hh * 4) * LL;
#pragma unroll
    for (int m = 0; m < 16; ++m) {
        int lm = 16 * w + 128 * m + n;
        float qv = qrow[lm];
        float kl = krow[lm];
        float vl0 = vb0[lm];
        float vl1 = vb0[(size_t)1 * LL + lm];
        float vl2 = vb0[(size_t)2 * LL + lm];
        float vl3 = vb0[(size_t)3 * LL + lm];
        float part0 = qv * (acc[m][0] + kl * vl0 * Dh);
        float part1 = qv * (acc[m][1] + kl * vl1 * Dh);
        float part2 = qv * (acc[m][2] + kl * vl2 * Dh);
        float part3 = qv * (acc[m][3] + kl * vl3 * Dh);
        part0 += __shfl_xor(part0, 16, 64); part0 += __shfl_xor(part0, 32, 64);
        part1 += __shfl_xor(part1, 16, 64); part1 += __shfl_xor(part1, 32, 64);
        part2 += __shfl_xor(part2, 16, 64); part2 += __shfl_xor(part2, 32, 64);
        part3 += __shfl_xor(part3, 16, 64); part3 += __shfl_xor(part3, 32, 64);
        float outv = (g == 0) ? part0 : (g == 1) ? part1 : (g == 2) ? part2 : part3;
        y_g[((size_t)b * DM + (size_t)g * 256 + hh) * LL + lm] = outv;
    }
}

// ---------------------------------------------------------------------------
extern "C" void kernel_launch(void* const* d_in, const int* in_sizes, int n_in,
                              void* d_out, int out_size, void* d_ws, size_t ws_size,
                              hipStream_t stream) {
    const float* u       = (const float*)d_in[0];
    const float* q_w     = (const float*)d_in[1];
    const float* q_b     = (const float*)d_in[2];
    const float* k_w     = (const float*)d_in[3];
    const float* k_b     = (const float*)d_in[4];
    const float* v_w     = (const float*)d_in[5];
    const float* v_b     = (const float*)d_in[6];
    const float* kern_k  = (const float*)d_in[7];
    const float* kern_v  = (const float*)d_in[8];
    const float* D_key   = (const float*)d_in[9];
    const float* D_v     = (const float*)d_in[10];
    const float* pw_w    = (const float*)d_in[11];
    const float* pw_b    = (const float*)d_in[12];
    float* out = (float*)d_out;

    const size_t BDL = (size_t)B_ * DM * LL;
    char* p = (char*)d_ws;
    float*          w_kv   = (float*)p;          p += (size_t)HH * LL * 4;
    unsigned short* w_kkey = (unsigned short*)p; p += (size_t)DM * LL * 2;
    unsigned short* w_wbuf = (unsigned short*)p; p += (size_t)DM * DM * 2;
    float*          w_R0   = (float*)p;          p += BDL * 4;
    float*          w_q    = (float*)p;          p += BDL * 4;
    float*          w_ky   = (float*)p;          p += BDL * 4;
    float*          w_v    = (float*)p;          p += BDL * 4;
    unsigned short* w_uT   = (unsigned short*)w_R0;
    unsigned short* w_ygT  = (unsigned short*)w_R0;
    float*          w_knew = w_R0;
    float*          w_yg   = w_ky;

    // 1. build kernels
    build_kernels_kernel<<<DM + HH, 256, 0, stream>>>(kern_k, kern_v, w_kkey, w_kv);

    // 2. u -> u_T bf16
    dim3 tgrid(LL / 64, DM / 64, B_);
    transpose_cvt_kernel<<<tgrid, 256, 0, stream>>>(u, w_uT, 0);

    // 3. projections (bf16 MFMA)
    dim3 ggrid(B_ * (LL / 128), DM / 128);
    wcvt_kernel<<<DM * DM / 1024, 256, 0, stream>>>(q_w, w_wbuf);
    gemm_mfma_kernel<<<ggrid, 256, 0, stream>>>(w_wbuf, w_uT, q_b, w_q);
    wcvt_kernel<<<DM * DM / 1024, 256, 0, stream>>>(k_w, w_wbuf);
    gemm_mfma_kernel<<<ggrid, 256, 0, stream>>>(w_wbuf, w_uT, k_b, w_ky);
    wcvt_kernel<<<DM * DM / 1024, 256, 0, stream>>>(v_w, w_wbuf);
    gemm_mfma_kernel<<<ggrid, 256, 0, stream>>>(w_wbuf, w_uT, v_b, w_v);

    // 4. key conv + skip via Toeplitz MFMA (u_T dead; knew takes over R0)
    key_conv_mfma_kernel<<<DM, 512, 0, stream>>>(w_ky, w_kkey, D_key, w_knew);

    // 5. value conv + gating via Toeplitz MFMA (y_g overwrites kraw)
    value_conv_mfma_kernel<<<B_ * HH, 512, 0, stream>>>(
        w_knew, w_v, w_q, w_kv, D_v, w_yg);

    // 6. y_g -> gelu -> yg_T bf16
    transpose_cvt_kernel<<<tgrid, 256, 0, stream>>>(w_yg, w_ygT, 1);

    // 7. pointwise projection
    wcvt_kernel<<<DM * DM / 1024, 256, 0, stream>>>(pw_w, w_wbuf);
    gemm_mfma_kernel<<<ggrid, 256, 0, stream>>>(w_wbuf, w_ygT, pw_b, out);
}